// Round 1
// baseline (1546.775 us; speedup 1.0000x reference)
//
#include <hip/hip_runtime.h>
#include <math.h>

#define BB 512
#define SS 200
#define DDIM 64
#define HD 32
#define LL 2
#define NROWS (BB * SS)   // 102400
#define EPS 1e-8f
#define CC 0.001f

// ---------------- static device buffers (activations) ----------------
__device__ float g_x[NROWS * DDIM];
__device__ float g_qin[NROWS * DDIM];
__device__ float g_q[NROWS * DDIM];
__device__ float g_k[NROWS * DDIM];
__device__ float g_v[NROWS * DDIM];
__device__ float g_ctx[NROWS * DDIM];

// ---------------- helpers ----------------
__device__ __forceinline__ float wave_sum(float v) {
#pragma unroll
    for (int o = 32; o > 0; o >>= 1) v += __shfl_xor(v, o, 64);
    return v;
}
__device__ __forceinline__ float wave_max(float v) {
#pragma unroll
    for (int o = 32; o > 0; o >>= 1) v = fmaxf(v, __shfl_xor(v, o, 64));
    return v;
}

// ---------------- zero accumulators ----------------
__global__ void zero_kernel(float* __restrict__ p, int n) {
    int i = blockIdx.x * 256 + threadIdx.x;
    if (i < n) p[i] = 0.f;
}

// ---------------- embedding ----------------
// x[b,s,:] = item_emb[log_seqs[b,s]] * 8 + pos_emb[(s+1)*(log!=0)]
__global__ __launch_bounds__(256) void embed_kernel(const int* __restrict__ log_seqs,
                                                    const float* __restrict__ item_emb,
                                                    const float* __restrict__ pos_emb,
                                                    float* __restrict__ x) {
    int tid = blockIdx.x * 256 + threadIdx.x;   // over NROWS*64
    int row = tid >> 6, d = tid & 63;
    int s = row % SS;
    int li = log_seqs[row];
    int poss = li ? (s + 1) : 0;
    x[tid] = item_emb[li * DDIM + d] * 8.0f + pos_emb[poss * DDIM + d];
}

// ---------------- LayerNorm (one wave per row, lane=dim) ----------------
__global__ __launch_bounds__(256) void ln_kernel(const float* __restrict__ in,
                                                 const float* __restrict__ w,
                                                 const float* __restrict__ b,
                                                 float* __restrict__ out) {
    int t = threadIdx.x;
    int row = blockIdx.x * 4 + (t >> 6);
    int lane = t & 63;
    long idx = (long)row * DDIM + lane;
    float x = in[idx];
    float m = wave_sum(x) * (1.f / 64.f);
    float dv = x - m;
    float var = wave_sum(dv * dv) * (1.f / 64.f);
    out[idx] = dv * rsqrtf(var + EPS) * w[lane] + b[lane];
}

// ---------------- 64x64 GEMM: out[r,c] = act(in[r,:].W[c,:] + bias[c] [+res]) ----------------
// EPI: 0 = none, 1 = relu, 2 = +res
template <int EPI>
__global__ __launch_bounds__(256) void gemm64(const float* __restrict__ in,
                                              const float* __restrict__ W,   // (64 out, 64 in) row-major
                                              const float* __restrict__ bias,
                                              const float* __restrict__ res,
                                              float* __restrict__ out) {
    __shared__ float in_s[64][68];
    __shared__ float wt_s[64][68];   // wt_s[d][c] = W[c*64+d]
    int t = threadIdx.x;
    long row0 = (long)blockIdx.x * 64;
    for (int idx = t; idx < 4096; idx += 256) {
        int c = idx >> 6, d = idx & 63;
        wt_s[d][c] = W[idx];
        in_s[c][d] = in[(row0 + c) * DDIM + d];
    }
    __syncthreads();
    int tx = t & 15, ty = t >> 4;
    int r0 = ty * 4, c0 = tx * 4;
    float acc[4][4] = {};
#pragma unroll
    for (int d = 0; d < 64; d += 4) {
        float4 a[4], wv[4];
#pragma unroll
        for (int i = 0; i < 4; ++i) a[i] = *(const float4*)&in_s[r0 + i][d];
#pragma unroll
        for (int tt = 0; tt < 4; ++tt) wv[tt] = *(const float4*)&wt_s[d + tt][c0];
#pragma unroll
        for (int i = 0; i < 4; ++i) {
            float av[4] = {a[i].x, a[i].y, a[i].z, a[i].w};
#pragma unroll
            for (int tt = 0; tt < 4; ++tt) {
                acc[i][0] += av[tt] * wv[tt].x;
                acc[i][1] += av[tt] * wv[tt].y;
                acc[i][2] += av[tt] * wv[tt].z;
                acc[i][3] += av[tt] * wv[tt].w;
            }
        }
    }
    float4 b4 = *(const float4*)&bias[c0];
    float bv[4] = {b4.x, b4.y, b4.z, b4.w};
#pragma unroll
    for (int i = 0; i < 4; ++i) {
        long gr = row0 + r0 + i;
        float4 o;
        float* op = (float*)&o;
#pragma unroll
        for (int j = 0; j < 4; ++j) {
            float v = acc[i][j] + bv[j];
            if (EPI == 1) v = fmaxf(v, 0.f);
            op[j] = v;
        }
        if (EPI == 2) {
            float4 r4 = *(const float4*)&res[gr * DDIM + c0];
            o.x += r4.x; o.y += r4.y; o.z += r4.z; o.w += r4.w;
        }
        *(float4*)&out[gr * DDIM + c0] = o;
    }
}

// ---------------- causal attention, one block per (b, head) ----------------
__global__ __launch_bounds__(256) void attn_kernel(const float* __restrict__ q,
                                                   const float* __restrict__ k,
                                                   const float* __restrict__ v,
                                                   float* __restrict__ ctx) {
    __shared__ float K_s[SS][33];
    __shared__ float V_s[SS][33];
    __shared__ float A_s[4][SS];
    int b = blockIdx.x >> 1, h = blockIdx.x & 1;
    int t = threadIdx.x;
    const long base = (long)b * SS * DDIM + h * HD;
    for (int idx = t; idx < SS * HD; idx += 256) {
        int kk = idx >> 5, d = idx & 31;
        K_s[kk][d] = k[base + kk * DDIM + d];
        V_s[kk][d] = v[base + kk * DDIM + d];
    }
    __syncthreads();
    int w = t >> 6, lane = t & 63;
    const float scale = 0.17677669529663687f;   // 1/sqrt(32)
    for (int r = w; r < SS; r += 4) {
        float qv[HD];
#pragma unroll
        for (int d = 0; d < HD; ++d) qv[d] = q[base + r * DDIM + d];
        float sc[4];
        float m = -1e30f;
#pragma unroll
        for (int c = 0; c < 4; ++c) {
            int kk = lane + c * 64;
            sc[c] = -1e30f;
            if (kk <= r) {
                float dot = 0.f;
#pragma unroll
                for (int d = 0; d < HD; ++d) dot += qv[d] * K_s[kk][d];
                sc[c] = dot * scale;
            }
            m = fmaxf(m, sc[c]);
        }
        m = wave_max(m);
        float sum = 0.f;
#pragma unroll
        for (int c = 0; c < 4; ++c) {
            int kk = lane + c * 64;
            if (kk <= r) { sc[c] = expf(sc[c] - m); sum += sc[c]; }
        }
        sum = wave_sum(sum);
        float inv = 1.f / sum;
#pragma unroll
        for (int c = 0; c < 4; ++c) {
            int kk = lane + c * 64;
            if (kk <= r) A_s[w][kk] = sc[c] * inv;
        }
        // ctx[d] = sum_kk A[kk] * V[kk][d]; lanes split kk parity
        int half = lane >> 5, d = lane & 31;
        float acc = 0.f;
        for (int kk = half; kk <= r; kk += 2) acc += A_s[w][kk] * V_s[kk][d];
        acc += __shfl_xor(acc, 32, 64);
        if (half == 0) ctx[base + r * DDIM + d] = acc;
    }
}

// ---------------- Gram matrix: out(64x64) += sum_r A[r,:]^T A[r,:] ----------------
__global__ __launch_bounds__(256) void gram_kernel(const float* __restrict__ A, int nrows,
                                                   float* __restrict__ out) {
    __shared__ float rows[8][64];
    int t = threadIdx.x;
    int i = t >> 2;            // 0..63
    int jb = (t & 3) * 16;     // 0/16/32/48
    float acc[16] = {};
    for (long base = (long)blockIdx.x * 8; base < nrows; base += (long)gridDim.x * 8) {
        for (int idx = t; idx < 512; idx += 256) {
            int rr = idx >> 6, d = idx & 63;
            long gr = base + rr;
            rows[rr][d] = (gr < nrows) ? A[gr * DDIM + d] : 0.f;
        }
        __syncthreads();
#pragma unroll
        for (int rr = 0; rr < 8; ++rr) {
            float ai = rows[rr][i];
#pragma unroll
            for (int j = 0; j < 16; ++j) acc[j] += ai * rows[rr][jb + j];
        }
        __syncthreads();
    }
#pragma unroll
    for (int j = 0; j < 16; ++j) atomicAdd(&out[i * 64 + jb + j], acc[j]);
}

// ---------------- right(): sum over rows of (1-C)ps^2 - 2ps ----------------
__global__ __launch_bounds__(256) void right_kernel(const float* __restrict__ x,
                                                    const float* __restrict__ item_emb,
                                                    const int* __restrict__ pos_seqs,
                                                    const float* __restrict__ pred_w,
                                                    float* __restrict__ right_acc) {
    __shared__ float p_s[64];
    int t = threadIdx.x;
    if (t < 64) p_s[t] = pred_w[t];
    __syncthreads();
    int w = t >> 6, lane = t & 63;
    float local = 0.f;
    for (long row = (long)blockIdx.x * 4 + w; row < NROWS; row += (long)gridDim.x * 4) {
        int pi = pos_seqs[row];
        float val = x[row * DDIM + lane] * item_emb[(long)pi * DDIM + lane] * p_s[lane];
        float ps = wave_sum(val);
        if (lane == 0) local += (1.0f - CC) * ps * ps - 2.0f * ps;
    }
    if (lane == 0) atomicAdd(right_acc, local);
}

// ---------------- per-parameter sum-of-squares (one block per tensor slice) ----------------
struct NormEntry { const float* p; int n; };
struct NormArgs { NormEntry e[30]; };

__global__ __launch_bounds__(256) void norms_kernel(NormArgs args, float* __restrict__ norms) {
    __shared__ float red[256];
    NormEntry en = args.e[blockIdx.x];
    float s = 0.f;
    for (int i = threadIdx.x; i < en.n; i += 256) { float v = en.p[i]; s += v * v; }
    red[threadIdx.x] = s;
    for (int o = 128; o > 0; o >>= 1) {
        __syncthreads();
        if (threadIdx.x < o) red[threadIdx.x] += red[threadIdx.x + o];
    }
    __syncthreads();
    if (threadIdx.x == 0) norms[blockIdx.x] = red[0];
}

// ---------------- final scalar ----------------
__global__ __launch_bounds__(256) void final_kernel(const float* __restrict__ EE,
                                                    const float* __restrict__ FF,
                                                    const float* __restrict__ pred_w,
                                                    const float* __restrict__ right_acc,
                                                    const float* __restrict__ norms,
                                                    float* __restrict__ out) {
    __shared__ float p_s[64];
    __shared__ float redL[256];
    __shared__ float redT[256];
    int t = threadIdx.x;
    if (t < 64) p_s[t] = pred_w[t];
    __syncthreads();
    float lf = 0.f, tr = 0.f;
    for (int p = t; p < 4096; p += 256) {
        int i = p >> 6, j = p & 63;
        float ee = EE[p];
        lf += FF[p] * ee * p_s[i] * p_s[j];
        if (i == j) tr += ee;
    }
    redL[t] = lf; redT[t] = tr;
    for (int o = 128; o > 0; o >>= 1) {
        __syncthreads();
        if (t < o) { redL[t] += redL[t + o]; redT[t] += redT[t + o]; }
    }
    __syncthreads();
    if (t == 0) {
        float reg = sqrtf(redT[0]);   // ||item_emb||_F = sqrt(trace(EE))
        for (int s = 0; s < 30; ++s) reg += sqrtf(norms[s]);
        out[0] = CC * redL[0] + right_acc[0] + 0.1f * reg;
    }
}

// ---------------- host ----------------
struct DevPtrs { float *x, *qin, *q, *k, *v, *ctx; };

static DevPtrs fetch_ptrs() {
    DevPtrs p;
    hipGetSymbolAddress((void**)&p.x,   HIP_SYMBOL(g_x));
    hipGetSymbolAddress((void**)&p.qin, HIP_SYMBOL(g_qin));
    hipGetSymbolAddress((void**)&p.q,   HIP_SYMBOL(g_q));
    hipGetSymbolAddress((void**)&p.k,   HIP_SYMBOL(g_k));
    hipGetSymbolAddress((void**)&p.v,   HIP_SYMBOL(g_v));
    hipGetSymbolAddress((void**)&p.ctx, HIP_SYMBOL(g_ctx));
    return p;
}

extern "C" void kernel_launch(void* const* d_in, const int* in_sizes, int n_in,
                              void* d_out, int out_size, void* d_ws, size_t ws_size,
                              hipStream_t stream) {
    const int*   log_seqs = (const int*)d_in[1];
    const int*   pos_seqs = (const int*)d_in[2];
    const float* item_emb = (const float*)d_in[3];
    const float* pos_emb  = (const float*)d_in[4];
    const float* pred_w   = (const float*)d_in[5];
    const float* ln_w     = (const float*)d_in[6];
    const float* ln_b     = (const float*)d_in[7];
    const float* qkv_w    = (const float*)d_in[8];
    const float* qkv_b    = (const float*)d_in[9];
    const float* out_w    = (const float*)d_in[10];
    const float* out_b    = (const float*)d_in[11];
    const float* fc1_w    = (const float*)d_in[12];
    const float* fc1_b    = (const float*)d_in[13];
    const float* ffln_w   = (const float*)d_in[14];
    const float* ffln_b   = (const float*)d_in[15];
    const float* fc2_w    = (const float*)d_in[16];
    const float* fc2_b    = (const float*)d_in[17];
    const float* ffln2_w  = (const float*)d_in[18];
    const float* ffln2_b  = (const float*)d_in[19];

    static DevPtrs P = fetch_ptrs();   // first call is the uncaptured correctness call

    float* ws   = (float*)d_ws;
    float* EE   = ws;            // 4096
    float* FF   = ws + 4096;     // 4096
    float* rAcc = ws + 8192;     // 1
    float* nrm  = ws + 8193;     // 30

    // zero accumulators (8223 floats)
    zero_kernel<<<33, 256, 0, stream>>>(ws, 8223);

    // embedding
    embed_kernel<<<NROWS * DDIM / 256, 256, 0, stream>>>(log_seqs, item_emb, pos_emb, P.x);

    const int GEMM_GRID = NROWS / 64;   // 1600
    const int LN_GRID   = NROWS / 4;    // 25600

    for (int l = 0; l < LL; ++l) {
        const float* Wqkv = qkv_w + (long)l * 3 * 64 * 64;
        const float* Bqkv = qkv_b + (long)l * 192;
        // q_in = LN(x)
        ln_kernel<<<LN_GRID, 256, 0, stream>>>(P.x, ln_w + l * 64, ln_b + l * 64, P.qin);
        // q,k,v
        gemm64<0><<<GEMM_GRID, 256, 0, stream>>>(P.qin, Wqkv,          Bqkv,       nullptr, P.q);
        gemm64<0><<<GEMM_GRID, 256, 0, stream>>>(P.x,   Wqkv + 4096,   Bqkv + 64,  nullptr, P.k);
        gemm64<0><<<GEMM_GRID, 256, 0, stream>>>(P.x,   Wqkv + 8192,   Bqkv + 128, nullptr, P.v);
        // attention
        attn_kernel<<<BB * 2, 256, 0, stream>>>(P.q, P.k, P.v, P.ctx);
        // x = q_in + ctx @ out_w^T + out_b
        gemm64<2><<<GEMM_GRID, 256, 0, stream>>>(P.ctx, out_w + (long)l * 4096, out_b + l * 64, P.qin, P.x);
        // h = relu(LN(x;ffln) @ fc1^T + fc1_b)
        ln_kernel<<<LN_GRID, 256, 0, stream>>>(P.x, ffln_w + l * 64, ffln_b + l * 64, P.v);
        gemm64<1><<<GEMM_GRID, 256, 0, stream>>>(P.v, fc1_w + (long)l * 4096, fc1_b + l * 64, nullptr, P.k);
        // x = h @ fc2^T + fc2_b + LN(x;ffln2)
        ln_kernel<<<LN_GRID, 256, 0, stream>>>(P.x, ffln2_w + l * 64, ffln2_b + l * 64, P.v);
        gemm64<2><<<GEMM_GRID, 256, 0, stream>>>(P.k, fc2_w + (long)l * 4096, fc2_b + l * 64, P.v, P.x);
    }

    // Gram matrices
    gram_kernel<<<256, 256, 0, stream>>>(item_emb, 100001, EE);
    gram_kernel<<<256, 256, 0, stream>>>(P.x, NROWS, FF);

    // right()
    right_kernel<<<256, 256, 0, stream>>>(P.x, item_emb, pos_seqs, pred_w, rAcc);

    // parameter norms (30 slices; item_emb handled via trace(EE))
    NormArgs na;
    int s = 0;
    na.e[s++] = {pos_emb, (SS + 1) * DDIM};
    na.e[s++] = {pred_w, DDIM};
    for (int l = 0; l < LL; ++l) {
        na.e[s++] = {ln_w + l * 64, 64};
        na.e[s++] = {ln_b + l * 64, 64};
        na.e[s++] = {qkv_w + (long)l * 12288, 12288};
        na.e[s++] = {qkv_b + (long)l * 192, 192};
        na.e[s++] = {out_w + (long)l * 4096, 4096};
        na.e[s++] = {out_b + l * 64, 64};
        na.e[s++] = {fc1_w + (long)l * 4096, 4096};
        na.e[s++] = {fc1_b + l * 64, 64};
        na.e[s++] = {ffln_w + l * 64, 64};
        na.e[s++] = {ffln_b + l * 64, 64};
        na.e[s++] = {fc2_w + (long)l * 4096, 4096};
        na.e[s++] = {fc2_b + l * 64, 64};
        na.e[s++] = {ffln2_w + l * 64, 64};
        na.e[s++] = {ffln2_b + l * 64, 64};
    }
    norms_kernel<<<30, 256, 0, stream>>>(na, nrm);

    // final scalar
    final_kernel<<<1, 256, 0, stream>>>(EE, FF, pred_w, rAcc, nrm, (float*)d_out);
}

// Round 3
// 1503.647 us; speedup vs baseline: 1.0287x; 1.0287x over previous
//
#include <hip/hip_runtime.h>
#include <math.h>

#define BB 512
#define SS 200
#define DDIM 64
#define HD 32
#define LL 2
#define NROWS (BB * SS)   // 102400
#define EPS 1e-8f
#define CC 0.001f

// ---------------- static device buffers (activations) ----------------
__device__ float g_x[NROWS * DDIM];
__device__ float g_qin[NROWS * DDIM];
__device__ float g_q[NROWS * DDIM];
__device__ float g_k[NROWS * DDIM];
__device__ float g_v[NROWS * DDIM];
__device__ float g_ctx[NROWS * DDIM];

// ---------------- helpers ----------------
__device__ __forceinline__ float wave_sum(float v) {
#pragma unroll
    for (int o = 32; o > 0; o >>= 1) v += __shfl_xor(v, o, 64);
    return v;
}
__device__ __forceinline__ float wave_max(float v) {
#pragma unroll
    for (int o = 32; o > 0; o >>= 1) v = fmaxf(v, __shfl_xor(v, o, 64));
    return v;
}

// ---------------- zero accumulators ----------------
__global__ void zero_kernel(float* __restrict__ p, int n) {
    int i = blockIdx.x * 256 + threadIdx.x;
    if (i < n) p[i] = 0.f;
}

// ---------------- embedding ----------------
__global__ __launch_bounds__(256) void embed_kernel(const int* __restrict__ log_seqs,
                                                    const float* __restrict__ item_emb,
                                                    const float* __restrict__ pos_emb,
                                                    float* __restrict__ x) {
    int tid = blockIdx.x * 256 + threadIdx.x;   // over NROWS*64
    int row = tid >> 6, d = tid & 63;
    int s = row % SS;
    int li = log_seqs[row];
    int poss = li ? (s + 1) : 0;
    x[tid] = item_emb[li * DDIM + d] * 8.0f + pos_emb[poss * DDIM + d];
}

// ---------------- in-tile LayerNorm: 256 threads, 64 rows x 64 cols, stride 68 ----------------
__device__ __forceinline__ void normalize_tile(float (* __restrict__ tile)[68],
                                               const float* __restrict__ w_s,
                                               const float* __restrict__ b_s,
                                               int t, float* __restrict__ save) {
    int r = t >> 2, qd = (t & 3) * 16;
    float4 v[4];
#pragma unroll
    for (int g = 0; g < 4; ++g) v[g] = *(const float4*)&tile[r][qd + g * 4];
    float s1 = 0.f, s2 = 0.f;
#pragma unroll
    for (int g = 0; g < 4; ++g) {
        s1 += (v[g].x + v[g].y) + (v[g].z + v[g].w);
        s2 += (v[g].x * v[g].x + v[g].y * v[g].y) + (v[g].z * v[g].z + v[g].w * v[g].w);
    }
    s1 += __shfl_xor(s1, 1, 64); s1 += __shfl_xor(s1, 2, 64);
    s2 += __shfl_xor(s2, 1, 64); s2 += __shfl_xor(s2, 2, 64);
    float m = s1 * (1.f / 64.f);
    float var = s2 * (1.f / 64.f) - m * m;
    float rs = rsqrtf(var + EPS);
#pragma unroll
    for (int g = 0; g < 4; ++g) {
        float4 w4 = *(const float4*)&w_s[qd + g * 4];
        float4 b4 = *(const float4*)&b_s[qd + g * 4];
        float4 o;
        o.x = (v[g].x - m) * rs * w4.x + b4.x;
        o.y = (v[g].y - m) * rs * w4.y + b4.y;
        o.z = (v[g].z - m) * rs * w4.z + b4.z;
        o.w = (v[g].w - m) * rs * w4.w + b4.w;
        *(float4*)&tile[r][qd + g * 4] = o;
        if (save) *(float4*)&save[r * DDIM + qd + g * 4] = o;
    }
}

// ---------------- fused 64x64 GEMM ----------------
// EPI: 0 none, 1 relu, 2 +res(raw, global), 3 +LN(res) (staged+normalized in LDS)
// LNIN: LayerNorm the input tile before GEMM.  SAVE: write normalized input to `save`.
template <int EPI, bool LNIN, bool SAVE>
__global__ __launch_bounds__(256) void gemmf(const float* __restrict__ in,
                                             const float* __restrict__ W,
                                             const float* __restrict__ bias,
                                             const float* __restrict__ lnw,
                                             const float* __restrict__ lnb,
                                             const float* __restrict__ res,
                                             const float* __restrict__ rlnw,
                                             const float* __restrict__ rlnb,
                                             float* __restrict__ save,
                                             float* __restrict__ out) {
    __shared__ float in_s[64][68];
    __shared__ float wt_s[64][68];   // wt_s[d][c] = W[c*64+d]
    __shared__ float res_s[EPI == 3 ? 64 : 1][68];
    __shared__ float lw_s[64], lb_s[64], rlw_s[64], rlb_s[64];
    int t = threadIdx.x;
    long row0 = (long)blockIdx.x * 64;
    for (int idx = t; idx < 4096; idx += 256) {
        int c = idx >> 6, d = idx & 63;
        wt_s[d][c] = W[idx];
        in_s[c][d] = in[(row0 + c) * DDIM + d];
        if constexpr (EPI == 3) res_s[c][d] = res[(row0 + c) * DDIM + d];
    }
    if constexpr (LNIN) { if (t < 64) { lw_s[t] = lnw[t]; lb_s[t] = lnb[t]; } }
    if constexpr (EPI == 3) { if (t < 64) { rlw_s[t] = rlnw[t]; rlb_s[t] = rlnb[t]; } }
    __syncthreads();
    if constexpr (LNIN || EPI == 3) {
        if constexpr (LNIN) normalize_tile(in_s, lw_s, lb_s, t, SAVE ? save + row0 * DDIM : nullptr);
        if constexpr (EPI == 3) normalize_tile(res_s, rlw_s, rlb_s, t, nullptr);
        __syncthreads();
    }
    int tx = t & 15, ty = t >> 4;
    int r0 = ty * 4, c0 = tx * 4;
    float acc[4][4] = {};
#pragma unroll
    for (int d = 0; d < 64; d += 4) {
        float4 a[4], wv[4];
#pragma unroll
        for (int i = 0; i < 4; ++i) a[i] = *(const float4*)&in_s[r0 + i][d];
#pragma unroll
        for (int tt = 0; tt < 4; ++tt) wv[tt] = *(const float4*)&wt_s[d + tt][c0];
#pragma unroll
        for (int i = 0; i < 4; ++i) {
            float av[4] = {a[i].x, a[i].y, a[i].z, a[i].w};
#pragma unroll
            for (int tt = 0; tt < 4; ++tt) {
                acc[i][0] += av[tt] * wv[tt].x;
                acc[i][1] += av[tt] * wv[tt].y;
                acc[i][2] += av[tt] * wv[tt].z;
                acc[i][3] += av[tt] * wv[tt].w;
            }
        }
    }
    float4 b4 = *(const float4*)&bias[c0];
    float bv[4] = {b4.x, b4.y, b4.z, b4.w};
#pragma unroll
    for (int i = 0; i < 4; ++i) {
        long gr = row0 + r0 + i;
        float4 o;
        float* op = (float*)&o;
#pragma unroll
        for (int j = 0; j < 4; ++j) {
            float v = acc[i][j] + bv[j];
            if constexpr (EPI == 1) v = fmaxf(v, 0.f);
            op[j] = v;
        }
        if constexpr (EPI == 2) {
            float4 r4 = *(const float4*)&res[gr * DDIM + c0];
            o.x += r4.x; o.y += r4.y; o.z += r4.z; o.w += r4.w;
        }
        if constexpr (EPI == 3) {
            float4 r4 = *(const float4*)&res_s[r0 + i][c0];
            o.x += r4.x; o.y += r4.y; o.z += r4.z; o.w += r4.w;
        }
        *(float4*)&out[gr * DDIM + c0] = o;
    }
}

// ---------------- fused K+V GEMM (shares input staging) ----------------
__global__ __launch_bounds__(256) void gemm_kv(const float* __restrict__ in,
                                               const float* __restrict__ Wk,
                                               const float* __restrict__ Wv,
                                               const float* __restrict__ bk,
                                               const float* __restrict__ bv,
                                               float* __restrict__ kout,
                                               float* __restrict__ vout) {
    __shared__ float in_s[64][68];
    __shared__ float wk_s[64][68];
    __shared__ float wv_s[64][68];
    int t = threadIdx.x;
    long row0 = (long)blockIdx.x * 64;
    for (int idx = t; idx < 4096; idx += 256) {
        int c = idx >> 6, d = idx & 63;
        wk_s[d][c] = Wk[idx];
        wv_s[d][c] = Wv[idx];
        in_s[c][d] = in[(row0 + c) * DDIM + d];
    }
    __syncthreads();
    int tx = t & 15, ty = t >> 4;
    int r0 = ty * 4, c0 = tx * 4;
    float acck[4][4] = {}, accv[4][4] = {};
#pragma unroll
    for (int d = 0; d < 64; d += 4) {
        float4 a[4], wkv[4], wvv[4];
#pragma unroll
        for (int i = 0; i < 4; ++i) a[i] = *(const float4*)&in_s[r0 + i][d];
#pragma unroll
        for (int tt = 0; tt < 4; ++tt) { wkv[tt] = *(const float4*)&wk_s[d + tt][c0]; wvv[tt] = *(const float4*)&wv_s[d + tt][c0]; }
#pragma unroll
        for (int i = 0; i < 4; ++i) {
            float av[4] = {a[i].x, a[i].y, a[i].z, a[i].w};
#pragma unroll
            for (int tt = 0; tt < 4; ++tt) {
                acck[i][0] += av[tt] * wkv[tt].x;
                acck[i][1] += av[tt] * wkv[tt].y;
                acck[i][2] += av[tt] * wkv[tt].z;
                acck[i][3] += av[tt] * wkv[tt].w;
                accv[i][0] += av[tt] * wvv[tt].x;
                accv[i][1] += av[tt] * wvv[tt].y;
                accv[i][2] += av[tt] * wvv[tt].z;
                accv[i][3] += av[tt] * wvv[tt].w;
            }
        }
    }
    float4 bk4 = *(const float4*)&bk[c0];
    float4 bv4 = *(const float4*)&bv[c0];
#pragma unroll
    for (int i = 0; i < 4; ++i) {
        long gr = row0 + r0 + i;
        float4 ok = make_float4(acck[i][0] + bk4.x, acck[i][1] + bk4.y, acck[i][2] + bk4.z, acck[i][3] + bk4.w);
        float4 ov = make_float4(accv[i][0] + bv4.x, accv[i][1] + bv4.y, accv[i][2] + bv4.z, accv[i][3] + bv4.w);
        *(float4*)&kout[gr * DDIM + c0] = ok;
        *(float4*)&vout[gr * DDIM + c0] = ov;
    }
}

// ---------------- causal attention, one block per (b, head) ----------------
// K staged as swizzled float4 (b128 reads, conflict-free); V plain stride-32;
// PV unrolled x4 with independent accumulators; causal chunk skipping.
__global__ __launch_bounds__(256) void attn_kernel(const float* __restrict__ q,
                                                   const float* __restrict__ k,
                                                   const float* __restrict__ v,
                                                   float* __restrict__ ctx) {
    __shared__ float K4[SS * 32];     // [(kk*8 + (dq^(kk&7)))*4 + e]
    __shared__ float V_s[SS * 32];    // [kk*32 + d]
    __shared__ float A_s[4][SS];
    int b = blockIdx.x >> 1, h = blockIdx.x & 1;
    int t = threadIdx.x;
    const long base = (long)b * (SS * DDIM) + h * HD;
    for (int i = t; i < SS * 8; i += 256) {          // 1600 float4s of K
        int kk = i >> 3, dq = i & 7;
        float4 k4 = *(const float4*)&k[base + kk * DDIM + dq * 4];
        *(float4*)&K4[(kk * 8 + (dq ^ (kk & 7))) * 4] = k4;
    }
    for (int i = t; i < SS * HD; i += 256) {
        int kk = i >> 5, d = i & 31;
        V_s[kk * 32 + d] = v[base + kk * DDIM + d];
    }
    __syncthreads();
    int w = t >> 6, lane = t & 63;
    const float scale = 0.17677669529663687f;   // 1/sqrt(32)
    const float* Aw = A_s[w];
    for (int r = w; r < SS; r += 4) {
        float4 qv4[8];
#pragma unroll
        for (int dq = 0; dq < 8; ++dq) qv4[dq] = *(const float4*)&q[base + r * DDIM + dq * 4];
        int ncb = (r >> 6) + 1;
        float sc[4];
        float m = -1e30f;
        for (int c = 0; c < ncb; ++c) {
            int kk = lane + c * 64;
            sc[c] = -1e30f;
            if (kk <= r) {
                int sw = kk & 7;
                float d0 = 0.f, d1 = 0.f, d2 = 0.f, d3 = 0.f;
#pragma unroll
                for (int dq = 0; dq < 8; ++dq) {
                    float4 k4 = *(const float4*)&K4[(kk * 8 + (dq ^ sw)) * 4];
                    d0 += qv4[dq].x * k4.x;
                    d1 += qv4[dq].y * k4.y;
                    d2 += qv4[dq].z * k4.z;
                    d3 += qv4[dq].w * k4.w;
                }
                sc[c] = ((d0 + d1) + (d2 + d3)) * scale;
            }
            m = fmaxf(m, sc[c]);
        }
        m = wave_max(m);
        float sum = 0.f;
        for (int c = 0; c < ncb; ++c) {
            int kk = lane + c * 64;
            if (kk <= r) { sc[c] = __expf(sc[c] - m); sum += sc[c]; }
        }
        sum = wave_sum(sum);
        float inv = 1.f / sum;
        for (int c = 0; c < ncb; ++c) {
            int kk = lane + c * 64;
            if (kk <= r) A_s[w][kk] = sc[c] * inv;
        }
        int half = lane >> 5, d = lane & 31;
        float a0 = 0.f, a1 = 0.f, a2 = 0.f, a3 = 0.f;
        int kk = half;
        for (; kk + 6 <= r; kk += 8) {
            a0 += Aw[kk]     * V_s[kk * 32 + d];
            a1 += Aw[kk + 2] * V_s[(kk + 2) * 32 + d];
            a2 += Aw[kk + 4] * V_s[(kk + 4) * 32 + d];
            a3 += Aw[kk + 6] * V_s[(kk + 6) * 32 + d];
        }
        for (; kk <= r; kk += 2) a0 += Aw[kk] * V_s[kk * 32 + d];
        float acc = (a0 + a1) + (a2 + a3);
        acc += __shfl_xor(acc, 32, 64);
        if (half == 0) ctx[base + r * DDIM + d] = acc;
    }
}

// ---------------- Gram matrix: out(64x64) += sum_r A[r,:]^T A[r,:] ----------------
__global__ __launch_bounds__(256) void gram_kernel(const float* __restrict__ A, int nrows,
                                                   float* __restrict__ out) {
    __shared__ float rows[8][64];
    int t = threadIdx.x;
    int i = t >> 2;            // 0..63
    int jb = (t & 3) * 16;     // 0/16/32/48
    float acc[16] = {};
    for (long base = (long)blockIdx.x * 8; base < nrows; base += (long)gridDim.x * 8) {
        for (int idx = t; idx < 512; idx += 256) {
            int rr = idx >> 6, d = idx & 63;
            long gr = base + rr;
            rows[rr][d] = (gr < nrows) ? A[gr * DDIM + d] : 0.f;
        }
        __syncthreads();
#pragma unroll
        for (int rr = 0; rr < 8; ++rr) {
            float ai = rows[rr][i];
#pragma unroll
            for (int j = 0; j < 16; ++j) acc[j] += ai * rows[rr][jb + j];
        }
        __syncthreads();
    }
#pragma unroll
    for (int j = 0; j < 16; ++j) atomicAdd(&out[i * 64 + jb + j], acc[j]);
}

// ---------------- right(): sum over rows of (1-C)ps^2 - 2ps ----------------
__global__ __launch_bounds__(256) void right_kernel(const float* __restrict__ x,
                                                    const float* __restrict__ item_emb,
                                                    const int* __restrict__ pos_seqs,
                                                    const float* __restrict__ pred_w,
                                                    float* __restrict__ right_acc) {
    __shared__ float p_s[64];
    int t = threadIdx.x;
    if (t < 64) p_s[t] = pred_w[t];
    __syncthreads();
    int w = t >> 6, lane = t & 63;
    float local = 0.f;
    for (long row = (long)blockIdx.x * 4 + w; row < NROWS; row += (long)gridDim.x * 4) {
        int pi = pos_seqs[row];
        float val = x[row * DDIM + lane] * item_emb[(long)pi * DDIM + lane] * p_s[lane];
        float ps = wave_sum(val);
        if (lane == 0) local += (1.0f - CC) * ps * ps - 2.0f * ps;
    }
    if (lane == 0) atomicAdd(right_acc, local);
}

// ---------------- per-parameter sum-of-squares ----------------
struct NormEntry { const float* p; int n; };
struct NormArgs { NormEntry e[30]; };

__global__ __launch_bounds__(256) void norms_kernel(NormArgs args, float* __restrict__ norms) {
    __shared__ float red[256];
    NormEntry en = args.e[blockIdx.x];
    float s = 0.f;
    for (int i = threadIdx.x; i < en.n; i += 256) { float v = en.p[i]; s += v * v; }
    red[threadIdx.x] = s;
    for (int o = 128; o > 0; o >>= 1) {
        __syncthreads();
        if (threadIdx.x < o) red[threadIdx.x] += red[threadIdx.x + o];
    }
    __syncthreads();
    if (threadIdx.x == 0) norms[blockIdx.x] = red[0];
}

// ---------------- final scalar ----------------
__global__ __launch_bounds__(256) void final_kernel(const float* __restrict__ EE,
                                                    const float* __restrict__ FF,
                                                    const float* __restrict__ pred_w,
                                                    const float* __restrict__ right_acc,
                                                    const float* __restrict__ norms,
                                                    float* __restrict__ out) {
    __shared__ float p_s[64];
    __shared__ float redL[256];
    __shared__ float redT[256];
    int t = threadIdx.x;
    if (t < 64) p_s[t] = pred_w[t];
    __syncthreads();
    float lf = 0.f, tr = 0.f;
    for (int p = t; p < 4096; p += 256) {
        int i = p >> 6, j = p & 63;
        float ee = EE[p];
        lf += FF[p] * ee * p_s[i] * p_s[j];
        if (i == j) tr += ee;
    }
    redL[t] = lf; redT[t] = tr;
    for (int o = 128; o > 0; o >>= 1) {
        __syncthreads();
        if (t < o) { redL[t] += redL[t + o]; redT[t] += redT[t + o]; }
    }
    __syncthreads();
    if (t == 0) {
        float reg = sqrtf(redT[0]);   // ||item_emb||_F = sqrt(trace(EE))
        for (int s = 0; s < 30; ++s) reg += sqrtf(norms[s]);
        out[0] = CC * redL[0] + right_acc[0] + 0.1f * reg;
    }
}

// ---------------- host ----------------
struct DevPtrs { float *x, *qin, *q, *k, *v, *ctx; };

static DevPtrs fetch_ptrs() {
    DevPtrs p;
    (void)hipGetSymbolAddress((void**)&p.x,   HIP_SYMBOL(g_x));
    (void)hipGetSymbolAddress((void**)&p.qin, HIP_SYMBOL(g_qin));
    (void)hipGetSymbolAddress((void**)&p.q,   HIP_SYMBOL(g_q));
    (void)hipGetSymbolAddress((void**)&p.k,   HIP_SYMBOL(g_k));
    (void)hipGetSymbolAddress((void**)&p.v,   HIP_SYMBOL(g_v));
    (void)hipGetSymbolAddress((void**)&p.ctx, HIP_SYMBOL(g_ctx));
    return p;
}

extern "C" void kernel_launch(void* const* d_in, const int* in_sizes, int n_in,
                              void* d_out, int out_size, void* d_ws, size_t ws_size,
                              hipStream_t stream) {
    const int*   log_seqs = (const int*)d_in[1];
    const int*   pos_seqs = (const int*)d_in[2];
    const float* item_emb = (const float*)d_in[3];
    const float* pos_emb  = (const float*)d_in[4];
    const float* pred_w   = (const float*)d_in[5];
    const float* ln_w     = (const float*)d_in[6];
    const float* ln_b     = (const float*)d_in[7];
    const float* qkv_w    = (const float*)d_in[8];
    const float* qkv_b    = (const float*)d_in[9];
    const float* out_w    = (const float*)d_in[10];
    const float* out_b    = (const float*)d_in[11];
    const float* fc1_w    = (const float*)d_in[12];
    const float* fc1_b    = (const float*)d_in[13];
    const float* ffln_w   = (const float*)d_in[14];
    const float* ffln_b   = (const float*)d_in[15];
    const float* fc2_w    = (const float*)d_in[16];
    const float* fc2_b    = (const float*)d_in[17];
    const float* ffln2_w  = (const float*)d_in[18];
    const float* ffln2_b  = (const float*)d_in[19];

    static DevPtrs P = fetch_ptrs();   // first call is the uncaptured correctness call

    float* ws   = (float*)d_ws;
    float* EE   = ws;            // 4096
    float* FF   = ws + 4096;     // 4096
    float* rAcc = ws + 8192;     // 1
    float* nrm  = ws + 8193;     // 30

    zero_kernel<<<33, 256, 0, stream>>>(ws, 8223);
    embed_kernel<<<NROWS * DDIM / 256, 256, 0, stream>>>(log_seqs, item_emb, pos_emb, P.x);

    const int GEMM_GRID = NROWS / 64;   // 1600

    for (int l = 0; l < LL; ++l) {
        const float* Wqkv = qkv_w + (long)l * 3 * 64 * 64;
        const float* Bqkv = qkv_b + (long)l * 192;
        // q = LN(x;ln) @ Wq^T + bq   (saves LN'd input to qin)
        gemmf<0, true, true><<<GEMM_GRID, 256, 0, stream>>>(
            P.x, Wqkv, Bqkv, ln_w + l * 64, ln_b + l * 64,
            nullptr, nullptr, nullptr, P.qin, P.q);
        // k,v = x @ {Wk,Wv}^T + {bk,bv}
        gemm_kv<<<GEMM_GRID, 256, 0, stream>>>(
            P.x, Wqkv + 4096, Wqkv + 8192, Bqkv + 64, Bqkv + 128, P.k, P.v);
        // attention
        attn_kernel<<<BB * 2, 256, 0, stream>>>(P.q, P.k, P.v, P.ctx);
        // x = qin + ctx @ out_w^T + out_b
        gemmf<2, false, false><<<GEMM_GRID, 256, 0, stream>>>(
            P.ctx, out_w + (long)l * 4096, out_b + l * 64, nullptr, nullptr,
            P.qin, nullptr, nullptr, nullptr, P.x);
        // h = relu(LN(x;ffln) @ fc1^T + fc1_b)
        gemmf<1, true, false><<<GEMM_GRID, 256, 0, stream>>>(
            P.x, fc1_w + (long)l * 4096, fc1_b + l * 64, ffln_w + l * 64, ffln_b + l * 64,
            nullptr, nullptr, nullptr, nullptr, P.k);
        // x = h @ fc2^T + fc2_b + LN(x;ffln2)
        gemmf<3, false, false><<<GEMM_GRID, 256, 0, stream>>>(
            P.k, fc2_w + (long)l * 4096, fc2_b + l * 64, nullptr, nullptr,
            P.x, ffln2_w + l * 64, ffln2_b + l * 64, nullptr, P.x);
    }

    gram_kernel<<<512, 256, 0, stream>>>(item_emb, 100001, EE);
    gram_kernel<<<512, 256, 0, stream>>>(P.x, NROWS, FF);
    right_kernel<<<512, 256, 0, stream>>>(P.x, item_emb, pos_seqs, pred_w, rAcc);

    NormArgs na;
    int s = 0;
    na.e[s++] = {pos_emb, (SS + 1) * DDIM};
    na.e[s++] = {pred_w, DDIM};
    for (int l = 0; l < LL; ++l) {
        na.e[s++] = {ln_w + l * 64, 64};
        na.e[s++] = {ln_b + l * 64, 64};
        na.e[s++] = {qkv_w + (long)l * 12288, 12288};
        na.e[s++] = {qkv_b + (long)l * 192, 192};
        na.e[s++] = {out_w + (long)l * 4096, 4096};
        na.e[s++] = {out_b + l * 64, 64};
        na.e[s++] = {fc1_w + (long)l * 4096, 4096};
        na.e[s++] = {fc1_b + l * 64, 64};
        na.e[s++] = {ffln_w + l * 64, 64};
        na.e[s++] = {ffln_b + l * 64, 64};
        na.e[s++] = {fc2_w + (long)l * 4096, 4096};
        na.e[s++] = {fc2_b + l * 64, 64};
        na.e[s++] = {ffln2_w + l * 64, 64};
        na.e[s++] = {ffln2_b + l * 64, 64};
    }
    norms_kernel<<<30, 256, 0, stream>>>(na, nrm);

    final_kernel<<<1, 256, 0, stream>>>(EE, FF, pred_w, rAcc, nrm, (float*)d_out);
}

// Round 4
// 1218.183 us; speedup vs baseline: 1.2697x; 1.2343x over previous
//
#include <hip/hip_runtime.h>
#include <math.h>

#define BB 512
#define SS 200
#define DDIM 64
#define HD 32
#define LL 2
#define NROWS (BB * SS)   // 102400
#define EPS 1e-8f
#define CC 0.001f

// ---------------- static device buffers (activations) ----------------
__device__ float g_x[NROWS * DDIM];
__device__ float g_qin[NROWS * DDIM];
__device__ float g_q[NROWS * DDIM];
__device__ float g_k[NROWS * DDIM];
__device__ float g_v[NROWS * DDIM];
__device__ float g_ctx[NROWS * DDIM];

// ---------------- helpers ----------------
__device__ __forceinline__ float wave_sum(float v) {
#pragma unroll
    for (int o = 32; o > 0; o >>= 1) v += __shfl_xor(v, o, 64);
    return v;
}
__device__ __forceinline__ float wave_max(float v) {
#pragma unroll
    for (int o = 32; o > 0; o >>= 1) v = fmaxf(v, __shfl_xor(v, o, 64));
    return v;
}

// ---------------- zero accumulators ----------------
__global__ void zero_kernel(float* __restrict__ p, int n) {
    int i = blockIdx.x * 256 + threadIdx.x;
    if (i < n) p[i] = 0.f;
}

// ---------------- embedding ----------------
__global__ __launch_bounds__(256) void embed_kernel(const int* __restrict__ log_seqs,
                                                    const float* __restrict__ item_emb,
                                                    const float* __restrict__ pos_emb,
                                                    float* __restrict__ x) {
    int tid = blockIdx.x * 256 + threadIdx.x;   // over NROWS*64
    int row = tid >> 6, d = tid & 63;
    int s = row % SS;
    int li = log_seqs[row];
    int poss = li ? (s + 1) : 0;
    x[tid] = item_emb[li * DDIM + d] * 8.0f + pos_emb[poss * DDIM + d];
}

// ---------------- tile staging helpers ----------------
// Stage a 64x64 activation tile (row-major) into LDS [64][68], float4 path.
__device__ __forceinline__ void stage_in(const float* __restrict__ G, float (* __restrict__ tile)[68],
                                         int t, long row0) {
#pragma unroll
    for (int rep = 0; rep < 4; ++rep) {
        int idx = t + rep * 256;
        int c = idx >> 4, d4 = (idx & 15) * 4;
        *(float4*)&tile[c][d4] = *(const float4*)&G[(row0 + c) * DDIM + d4];
    }
}

// Stage W (64 out x 64 in, row-major) TRANSPOSED into wt[d][c], via 4x4 block transpose
// (float4 reads + float4 LDS writes; 2-way bank aliasing only).
__device__ __forceinline__ void stage_wT(const float* __restrict__ Wg, float (* __restrict__ wt)[68], int t) {
    int bi = t & 15, bj = t >> 4;   // bi: c-block, bj: d-block
    float rv[4][4];
#pragma unroll
    for (int e = 0; e < 4; ++e)
        *(float4*)rv[e] = *(const float4*)&Wg[(bi * 4 + e) * DDIM + bj * 4];
#pragma unroll
    for (int e = 0; e < 4; ++e) {
        float4 o;
        o.x = rv[0][e]; o.y = rv[1][e]; o.z = rv[2][e]; o.w = rv[3][e];
        *(float4*)&wt[bj * 4 + e][bi * 4] = o;
    }
}

// acc[i][j] += sum_d A[r0+i][d] * W[d][c0+j]   (W stored transposed: wt[d][c])
__device__ __forceinline__ void gemm_tile(const float (* __restrict__ A)[68],
                                          const float (* __restrict__ W)[68],
                                          int r0, int c0, float acc[4][4]) {
#pragma unroll
    for (int d = 0; d < 64; d += 4) {
        float4 a[4], wv[4];
#pragma unroll
        for (int i = 0; i < 4; ++i) a[i] = *(const float4*)&A[r0 + i][d];
#pragma unroll
        for (int tt = 0; tt < 4; ++tt) wv[tt] = *(const float4*)&W[d + tt][c0];
#pragma unroll
        for (int i = 0; i < 4; ++i) {
            float av[4] = {a[i].x, a[i].y, a[i].z, a[i].w};
#pragma unroll
            for (int tt = 0; tt < 4; ++tt) {
                acc[i][0] += av[tt] * wv[tt].x;
                acc[i][1] += av[tt] * wv[tt].y;
                acc[i][2] += av[tt] * wv[tt].z;
                acc[i][3] += av[tt] * wv[tt].w;
            }
        }
    }
}

// LayerNorm rows of src -> dst (thread t owns row t>>2, 16-col chunk (t&3)*16).
// save (if non-null, pre-offset by row0*DDIM): also write normalized rows to global.
__device__ __forceinline__ void ln_rows(const float (* __restrict__ src)[68], float (* __restrict__ dst)[68],
                                        const float* __restrict__ w_s, const float* __restrict__ b_s,
                                        int t, float* __restrict__ save) {
    int rr = t >> 2, qd = (t & 3) * 16;
    float4 v[4];
#pragma unroll
    for (int g = 0; g < 4; ++g) v[g] = *(const float4*)&src[rr][qd + g * 4];
    float s1 = 0.f, s2 = 0.f;
#pragma unroll
    for (int g = 0; g < 4; ++g) {
        s1 += (v[g].x + v[g].y) + (v[g].z + v[g].w);
        s2 += (v[g].x * v[g].x + v[g].y * v[g].y) + (v[g].z * v[g].z + v[g].w * v[g].w);
    }
    s1 += __shfl_xor(s1, 1, 64); s1 += __shfl_xor(s1, 2, 64);
    s2 += __shfl_xor(s2, 1, 64); s2 += __shfl_xor(s2, 2, 64);
    float m = s1 * (1.f / 64.f);
    float var = s2 * (1.f / 64.f) - m * m;
    float rs = rsqrtf(var + EPS);
#pragma unroll
    for (int g = 0; g < 4; ++g) {
        float4 w4 = *(const float4*)&w_s[qd + g * 4];
        float4 b4 = *(const float4*)&b_s[qd + g * 4];
        float4 o;
        o.x = (v[g].x - m) * rs * w4.x + b4.x;
        o.y = (v[g].y - m) * rs * w4.y + b4.y;
        o.z = (v[g].z - m) * rs * w4.z + b4.z;
        o.w = (v[g].w - m) * rs * w4.w + b4.w;
        *(float4*)&dst[rr][qd + g * 4] = o;
        if (save) *(float4*)&save[rr * DDIM + qd + g * 4] = o;
    }
}

// Dual LayerNorm: a := LN1(a), b := LN2(a_old)  (same stats, different scale/shift)
__device__ __forceinline__ void ln_rows2(float (* __restrict__ a)[68], float (* __restrict__ b)[68],
                                         const float* __restrict__ w1, const float* __restrict__ b1,
                                         const float* __restrict__ w2, const float* __restrict__ b2, int t) {
    int rr = t >> 2, qd = (t & 3) * 16;
    float4 v[4];
#pragma unroll
    for (int g = 0; g < 4; ++g) v[g] = *(const float4*)&a[rr][qd + g * 4];
    float s1 = 0.f, s2 = 0.f;
#pragma unroll
    for (int g = 0; g < 4; ++g) {
        s1 += (v[g].x + v[g].y) + (v[g].z + v[g].w);
        s2 += (v[g].x * v[g].x + v[g].y * v[g].y) + (v[g].z * v[g].z + v[g].w * v[g].w);
    }
    s1 += __shfl_xor(s1, 1, 64); s1 += __shfl_xor(s1, 2, 64);
    s2 += __shfl_xor(s2, 1, 64); s2 += __shfl_xor(s2, 2, 64);
    float m = s1 * (1.f / 64.f);
    float var = s2 * (1.f / 64.f) - m * m;
    float rs = rsqrtf(var + EPS);
#pragma unroll
    for (int g = 0; g < 4; ++g) {
        float4 w14 = *(const float4*)&w1[qd + g * 4];
        float4 b14 = *(const float4*)&b1[qd + g * 4];
        float4 w24 = *(const float4*)&w2[qd + g * 4];
        float4 b24 = *(const float4*)&b2[qd + g * 4];
        float nx = (v[g].x - m) * rs, ny = (v[g].y - m) * rs, nz = (v[g].z - m) * rs, nw = (v[g].w - m) * rs;
        float4 o1, o2;
        o1.x = nx * w14.x + b14.x; o1.y = ny * w14.y + b14.y; o1.z = nz * w14.z + b14.z; o1.w = nw * w14.w + b14.w;
        o2.x = nx * w24.x + b24.x; o2.y = ny * w24.y + b24.y; o2.z = nz * w24.z + b24.z; o2.w = nw * w24.w + b24.w;
        *(float4*)&a[rr][qd + g * 4] = o1;
        *(float4*)&b[rr][qd + g * 4] = o2;
    }
}

// ---------------- fused QKV: stage x once; q = LN(x)@Wq, k,v = x@{Wk,Wv} ----------------
__global__ __launch_bounds__(256) void qkv_fused(const float* __restrict__ x,
                                                 const float* __restrict__ Wqkv,
                                                 const float* __restrict__ Bqkv,
                                                 const float* __restrict__ lnw,
                                                 const float* __restrict__ lnb,
                                                 float* __restrict__ qin,
                                                 float* __restrict__ qo,
                                                 float* __restrict__ ko,
                                                 float* __restrict__ vo) {
    __shared__ float A[64][68], B[64][68], W[64][68];
    __shared__ float lw[64], lb[64];
    int t = threadIdx.x;
    long row0 = (long)blockIdx.x * 64;
    stage_in(x, A, t, row0);
    stage_wT(Wqkv, W, t);
    if (t < 64) { lw[t] = lnw[t]; lb[t] = lnb[t]; }
    __syncthreads();
    ln_rows(A, B, lw, lb, t, qin + row0 * DDIM);
    __syncthreads();
    int tx = t & 15, ty = t >> 4, r0 = ty * 4, c0 = tx * 4;
    {
        float acc[4][4] = {};
        gemm_tile(B, W, r0, c0, acc);
        float4 b4 = *(const float4*)&Bqkv[c0];
        float bv[4] = {b4.x, b4.y, b4.z, b4.w};
#pragma unroll
        for (int i = 0; i < 4; ++i) {
            float4 o; o.x = acc[i][0] + bv[0]; o.y = acc[i][1] + bv[1]; o.z = acc[i][2] + bv[2]; o.w = acc[i][3] + bv[3];
            *(float4*)&qo[(row0 + r0 + i) * DDIM + c0] = o;
        }
    }
    __syncthreads();
    stage_wT(Wqkv + 4096, W, t);
    __syncthreads();
    {
        float acc[4][4] = {};
        gemm_tile(A, W, r0, c0, acc);
        float4 b4 = *(const float4*)&Bqkv[64 + c0];
        float bv[4] = {b4.x, b4.y, b4.z, b4.w};
#pragma unroll
        for (int i = 0; i < 4; ++i) {
            float4 o; o.x = acc[i][0] + bv[0]; o.y = acc[i][1] + bv[1]; o.z = acc[i][2] + bv[2]; o.w = acc[i][3] + bv[3];
            *(float4*)&ko[(row0 + r0 + i) * DDIM + c0] = o;
        }
    }
    __syncthreads();
    stage_wT(Wqkv + 8192, W, t);
    __syncthreads();
    {
        float acc[4][4] = {};
        gemm_tile(A, W, r0, c0, acc);
        float4 b4 = *(const float4*)&Bqkv[128 + c0];
        float bv[4] = {b4.x, b4.y, b4.z, b4.w};
#pragma unroll
        for (int i = 0; i < 4; ++i) {
            float4 o; o.x = acc[i][0] + bv[0]; o.y = acc[i][1] + bv[1]; o.z = acc[i][2] + bv[2]; o.w = acc[i][3] + bv[3];
            *(float4*)&vo[(row0 + r0 + i) * DDIM + c0] = o;
        }
    }
}

// ---------------- fused out-proj + FFN ----------------
// x1 = qin + ctx@Wo^T + bo;  h = relu(LN1(x1)@W1^T + b1);  x = h@W2^T + b2 + LN2(x1)
__global__ __launch_bounds__(256) void ffn_fused(const float* __restrict__ ctx,
                                                 const float* __restrict__ qin,
                                                 const float* __restrict__ Wo, const float* __restrict__ bo,
                                                 const float* __restrict__ W1, const float* __restrict__ b1,
                                                 const float* __restrict__ W2, const float* __restrict__ b2,
                                                 const float* __restrict__ l1w, const float* __restrict__ l1b,
                                                 const float* __restrict__ l2w, const float* __restrict__ l2b,
                                                 float* __restrict__ xout) {
    __shared__ float A[64][68], B[64][68], W[64][68];
    __shared__ float w1s[64], b1s[64], w2s[64], b2s[64];
    int t = threadIdx.x;
    long row0 = (long)blockIdx.x * 64;
    stage_in(ctx, A, t, row0);
    stage_in(qin, B, t, row0);
    stage_wT(Wo, W, t);
    if (t < 64) { w1s[t] = l1w[t]; b1s[t] = l1b[t]; w2s[t] = l2w[t]; b2s[t] = l2b[t]; }
    __syncthreads();
    int tx = t & 15, ty = t >> 4, r0 = ty * 4, c0 = tx * 4;
    // GEMM1: x1 = ctx@Wo + bo + qin
    float x1[4][4] = {};
    gemm_tile(A, W, r0, c0, x1);
    {
        float4 b4 = *(const float4*)&bo[c0];
        float bv[4] = {b4.x, b4.y, b4.z, b4.w};
#pragma unroll
        for (int i = 0; i < 4; ++i)
#pragma unroll
            for (int j = 0; j < 4; ++j) x1[i][j] += bv[j] + B[r0 + i][c0 + j];
    }
    __syncthreads();   // all reads of A/B/W done
#pragma unroll
    for (int i = 0; i < 4; ++i) {
        float4 o; o.x = x1[i][0]; o.y = x1[i][1]; o.z = x1[i][2]; o.w = x1[i][3];
        *(float4*)&A[r0 + i][c0] = o;
    }
    __syncthreads();   // x1 visible
    ln_rows2(A, B, w1s, b1s, w2s, b2s, t);   // A := LN1(x1), B := LN2(x1)
    stage_wT(W1, W, t);
    __syncthreads();
    // GEMM2: h = relu(LN1(x1)@W1 + b1)
    float h[4][4] = {};
    gemm_tile(A, W, r0, c0, h);
    {
        float4 b4 = *(const float4*)&b1[c0];
        float bv[4] = {b4.x, b4.y, b4.z, b4.w};
#pragma unroll
        for (int i = 0; i < 4; ++i)
#pragma unroll
            for (int j = 0; j < 4; ++j) h[i][j] = fmaxf(h[i][j] + bv[j], 0.f);
    }
    __syncthreads();
#pragma unroll
    for (int i = 0; i < 4; ++i) {
        float4 o; o.x = h[i][0]; o.y = h[i][1]; o.z = h[i][2]; o.w = h[i][3];
        *(float4*)&A[r0 + i][c0] = o;
    }
    stage_wT(W2, W, t);
    __syncthreads();
    // GEMM3: x = h@W2 + b2 + LN2(x1)
    float o3[4][4] = {};
    gemm_tile(A, W, r0, c0, o3);
    {
        float4 b4 = *(const float4*)&b2[c0];
        float bv[4] = {b4.x, b4.y, b4.z, b4.w};
#pragma unroll
        for (int i = 0; i < 4; ++i) {
            float4 o;
            o.x = o3[i][0] + bv[0] + B[r0 + i][c0 + 0];
            o.y = o3[i][1] + bv[1] + B[r0 + i][c0 + 1];
            o.z = o3[i][2] + bv[2] + B[r0 + i][c0 + 2];
            o.w = o3[i][3] + bv[3] + B[r0 + i][c0 + 3];
            *(float4*)&xout[(row0 + r0 + i) * DDIM + c0] = o;
        }
    }
}

// ---------------- causal attention, one block per (b, head), 8 waves ----------------
__global__ __launch_bounds__(512) void attn_kernel(const float* __restrict__ q,
                                                   const float* __restrict__ k,
                                                   const float* __restrict__ v,
                                                   float* __restrict__ ctx) {
    __shared__ float K4[SS * 32];     // [(kk*8 + (dq^(kk&7)))*4 + e]
    __shared__ float V_s[SS * 32];    // [kk*32 + d]
    __shared__ float A_s[8][SS];
    int b = blockIdx.x >> 1, h = blockIdx.x & 1;
    int t = threadIdx.x;
    const long base = (long)b * (SS * DDIM) + h * HD;
    for (int i = t; i < SS * 8; i += 512) {          // 1600 float4s of K
        int kk = i >> 3, dq = i & 7;
        float4 k4 = *(const float4*)&k[base + kk * DDIM + dq * 4];
        *(float4*)&K4[(kk * 8 + (dq ^ (kk & 7))) * 4] = k4;
    }
    for (int i = t; i < SS * HD; i += 512) {
        int kk = i >> 5, d = i & 31;
        V_s[kk * 32 + d] = v[base + kk * DDIM + d];
    }
    __syncthreads();
    int w = t >> 6, lane = t & 63;
    const float scale = 0.17677669529663687f;   // 1/sqrt(32)
    const float* Aw = A_s[w];
    for (int r = w; r < SS; r += 8) {
        float4 qv4[8];
#pragma unroll
        for (int dq = 0; dq < 8; ++dq) qv4[dq] = *(const float4*)&q[base + r * DDIM + dq * 4];
        int ncb = (r >> 6) + 1;
        float sc[4];
        float m = -1e30f;
        for (int c = 0; c < ncb; ++c) {
            int kk = lane + c * 64;
            sc[c] = -1e30f;
            if (kk <= r) {
                int sw = kk & 7;
                float d0 = 0.f, d1 = 0.f, d2 = 0.f, d3 = 0.f;
#pragma unroll
                for (int dq = 0; dq < 8; ++dq) {
                    float4 k4 = *(const float4*)&K4[(kk * 8 + (dq ^ sw)) * 4];
                    d0 += qv4[dq].x * k4.x;
                    d1 += qv4[dq].y * k4.y;
                    d2 += qv4[dq].z * k4.z;
                    d3 += qv4[dq].w * k4.w;
                }
                sc[c] = ((d0 + d1) + (d2 + d3)) * scale;
            }
            m = fmaxf(m, sc[c]);
        }
        m = wave_max(m);
        float sum = 0.f;
        for (int c = 0; c < ncb; ++c) {
            int kk = lane + c * 64;
            if (kk <= r) { sc[c] = __expf(sc[c] - m); sum += sc[c]; }
        }
        sum = wave_sum(sum);
        float inv = 1.f / sum;
        for (int c = 0; c < ncb; ++c) {
            int kk = lane + c * 64;
            if (kk <= r) A_s[w][kk] = sc[c] * inv;
        }
        int half = lane >> 5, d = lane & 31;
        float a0 = 0.f, a1 = 0.f, a2 = 0.f, a3 = 0.f;
        int kk = half;
        for (; kk + 6 <= r; kk += 8) {
            a0 += Aw[kk]     * V_s[kk * 32 + d];
            a1 += Aw[kk + 2] * V_s[(kk + 2) * 32 + d];
            a2 += Aw[kk + 4] * V_s[(kk + 4) * 32 + d];
            a3 += Aw[kk + 6] * V_s[(kk + 6) * 32 + d];
        }
        for (; kk <= r; kk += 2) a0 += Aw[kk] * V_s[kk * 32 + d];
        float acc = (a0 + a1) + (a2 + a3);
        acc += __shfl_xor(acc, 32, 64);
        if (half == 0) ctx[base + r * DDIM + d] = acc;
    }
}

// ---------------- Gram matrix: out(64x64) += sum_r A[r,:]^T A[r,:] ----------------
__global__ __launch_bounds__(256) void gram_kernel(const float* __restrict__ A, int nrows,
                                                   float* __restrict__ out) {
    __shared__ float rows[8][64];
    int t = threadIdx.x;
    int i = t >> 2;            // 0..63
    int jb = (t & 3) * 16;     // 0/16/32/48
    float acc[16] = {};
    for (long base = (long)blockIdx.x * 8; base < nrows; base += (long)gridDim.x * 8) {
        for (int idx = t; idx < 512; idx += 256) {
            int rr = idx >> 6, d = idx & 63;
            long gr = base + rr;
            rows[rr][d] = (gr < nrows) ? A[gr * DDIM + d] : 0.f;
        }
        __syncthreads();
#pragma unroll
        for (int rr = 0; rr < 8; ++rr) {
            float ai = rows[rr][i];
#pragma unroll
            for (int j = 0; j < 16; ++j) acc[j] += ai * rows[rr][jb + j];
        }
        __syncthreads();
    }
#pragma unroll
    for (int j = 0; j < 16; ++j) atomicAdd(&out[i * 64 + jb + j], acc[j]);
}

// ---------------- right(): per-block partial sums of (1-C)ps^2 - 2ps ----------------
__global__ __launch_bounds__(256) void right_kernel(const float* __restrict__ x,
                                                    const float* __restrict__ item_emb,
                                                    const int* __restrict__ pos_seqs,
                                                    const float* __restrict__ pred_w,
                                                    float* __restrict__ rpart) {
    __shared__ float p_s[64];
    __shared__ float red[4];
    int t = threadIdx.x;
    if (t < 64) p_s[t] = pred_w[t];
    __syncthreads();
    int w = t >> 6, lane = t & 63;
    float local = 0.f;
    for (long row = (long)blockIdx.x * 4 + w; row < NROWS; row += (long)gridDim.x * 4) {
        int pi = pos_seqs[row];
        float val = x[row * DDIM + lane] * item_emb[(long)pi * DDIM + lane] * p_s[lane];
        float ps = wave_sum(val);
        local += (1.0f - CC) * ps * ps - 2.0f * ps;   // all lanes hold same ps
    }
    local *= (1.f / 64.f);   // each of 64 lanes accumulated the same value
    local = wave_sum(local); // now lane-uniform again; cheap way to keep exactness: sum/64
    if (lane == 0) red[w] = local * (1.f / 64.f);
    __syncthreads();
    if (t == 0) rpart[blockIdx.x] = red[0] + red[1] + red[2] + red[3];
}

// ---------------- per-parameter sum-of-squares ----------------
struct NormEntry { const float* p; int n; };
struct NormArgs { NormEntry e[30]; };

__global__ __launch_bounds__(256) void norms_kernel(NormArgs args, float* __restrict__ norms) {
    __shared__ float red[256];
    NormEntry en = args.e[blockIdx.x];
    float s = 0.f;
    for (int i = threadIdx.x; i < en.n; i += 256) { float v = en.p[i]; s += v * v; }
    red[threadIdx.x] = s;
    for (int o = 128; o > 0; o >>= 1) {
        __syncthreads();
        if (threadIdx.x < o) red[threadIdx.x] += red[threadIdx.x + o];
    }
    __syncthreads();
    if (threadIdx.x == 0) norms[blockIdx.x] = red[0];
}

// ---------------- final scalar ----------------
__global__ __launch_bounds__(256) void final_kernel(const float* __restrict__ EE,
                                                    const float* __restrict__ FF,
                                                    const float* __restrict__ pred_w,
                                                    const float* __restrict__ rpart,
                                                    const float* __restrict__ norms,
                                                    float* __restrict__ out) {
    __shared__ float p_s[64];
    __shared__ float redL[256];
    __shared__ float redT[256];
    __shared__ float redR[256];
    int t = threadIdx.x;
    if (t < 64) p_s[t] = pred_w[t];
    __syncthreads();
    float lf = 0.f, tr = 0.f, rs = 0.f;
    for (int p = t; p < 4096; p += 256) {
        int i = p >> 6, j = p & 63;
        float ee = EE[p];
        lf += FF[p] * ee * p_s[i] * p_s[j];
        if (i == j) tr += ee;
    }
    for (int i = t; i < 1024; i += 256) rs += rpart[i];
    redL[t] = lf; redT[t] = tr; redR[t] = rs;
    for (int o = 128; o > 0; o >>= 1) {
        __syncthreads();
        if (t < o) { redL[t] += redL[t + o]; redT[t] += redT[t + o]; redR[t] += redR[t + o]; }
    }
    __syncthreads();
    if (t == 0) {
        float reg = sqrtf(redT[0]);   // ||item_emb||_F = sqrt(trace(EE))
        for (int s = 0; s < 30; ++s) reg += sqrtf(norms[s]);
        out[0] = CC * redL[0] + redR[0] + 0.1f * reg;
    }
}

// ---------------- host ----------------
struct DevPtrs { float *x, *qin, *q, *k, *v, *ctx; };

static DevPtrs fetch_ptrs() {
    DevPtrs p;
    (void)hipGetSymbolAddress((void**)&p.x,   HIP_SYMBOL(g_x));
    (void)hipGetSymbolAddress((void**)&p.qin, HIP_SYMBOL(g_qin));
    (void)hipGetSymbolAddress((void**)&p.q,   HIP_SYMBOL(g_q));
    (void)hipGetSymbolAddress((void**)&p.k,   HIP_SYMBOL(g_k));
    (void)hipGetSymbolAddress((void**)&p.v,   HIP_SYMBOL(g_v));
    (void)hipGetSymbolAddress((void**)&p.ctx, HIP_SYMBOL(g_ctx));
    return p;
}

extern "C" void kernel_launch(void* const* d_in, const int* in_sizes, int n_in,
                              void* d_out, int out_size, void* d_ws, size_t ws_size,
                              hipStream_t stream) {
    const int*   log_seqs = (const int*)d_in[1];
    const int*   pos_seqs = (const int*)d_in[2];
    const float* item_emb = (const float*)d_in[3];
    const float* pos_emb  = (const float*)d_in[4];
    const float* pred_w   = (const float*)d_in[5];
    const float* ln_w     = (const float*)d_in[6];
    const float* ln_b     = (const float*)d_in[7];
    const float* qkv_w    = (const float*)d_in[8];
    const float* qkv_b    = (const float*)d_in[9];
    const float* out_w    = (const float*)d_in[10];
    const float* out_b    = (const float*)d_in[11];
    const float* fc1_w    = (const float*)d_in[12];
    const float* fc1_b    = (const float*)d_in[13];
    const float* ffln_w   = (const float*)d_in[14];
    const float* ffln_b   = (const float*)d_in[15];
    const float* fc2_w    = (const float*)d_in[16];
    const float* fc2_b    = (const float*)d_in[17];
    const float* ffln2_w  = (const float*)d_in[18];
    const float* ffln2_b  = (const float*)d_in[19];

    static DevPtrs P = fetch_ptrs();   // first call is the uncaptured correctness call

    float* ws    = (float*)d_ws;
    float* EE    = ws;            // 4096
    float* FF    = ws + 4096;     // 4096
    float* rpart = ws + 8192;     // 1024
    float* nrm   = ws + 9216;     // 30

    zero_kernel<<<32, 256, 0, stream>>>(ws, 8192);   // EE + FF only; rpart/nrm fully written
    embed_kernel<<<NROWS * DDIM / 256, 256, 0, stream>>>(log_seqs, item_emb, pos_emb, P.x);

    const int GEMM_GRID = NROWS / 64;   // 1600

    for (int l = 0; l < LL; ++l) {
        const float* Wqkv = qkv_w + (long)l * 3 * 64 * 64;
        const float* Bqkv = qkv_b + (long)l * 192;
        qkv_fused<<<GEMM_GRID, 256, 0, stream>>>(
            P.x, Wqkv, Bqkv, ln_w + l * 64, ln_b + l * 64, P.qin, P.q, P.k, P.v);
        attn_kernel<<<BB * 2, 512, 0, stream>>>(P.q, P.k, P.v, P.ctx);
        ffn_fused<<<GEMM_GRID, 256, 0, stream>>>(
            P.ctx, P.qin,
            out_w + (long)l * 4096, out_b + l * 64,
            fc1_w + (long)l * 4096, fc1_b + l * 64,
            fc2_w + (long)l * 4096, fc2_b + l * 64,
            ffln_w + l * 64, ffln_b + l * 64,
            ffln2_w + l * 64, ffln2_b + l * 64,
            P.x);
    }

    gram_kernel<<<512, 256, 0, stream>>>(item_emb, 100001, EE);
    gram_kernel<<<512, 256, 0, stream>>>(P.x, NROWS, FF);
    right_kernel<<<1024, 256, 0, stream>>>(P.x, item_emb, pos_seqs, pred_w, rpart);

    NormArgs na;
    int s = 0;
    na.e[s++] = {pos_emb, (SS + 1) * DDIM};
    na.e[s++] = {pred_w, DDIM};
    for (int l = 0; l < LL; ++l) {
        na.e[s++] = {ln_w + l * 64, 64};
        na.e[s++] = {ln_b + l * 64, 64};
        na.e[s++] = {qkv_w + (long)l * 12288, 12288};
        na.e[s++] = {qkv_b + (long)l * 192, 192};
        na.e[s++] = {out_w + (long)l * 4096, 4096};
        na.e[s++] = {out_b + l * 64, 64};
        na.e[s++] = {fc1_w + (long)l * 4096, 4096};
        na.e[s++] = {fc1_b + l * 64, 64};
        na.e[s++] = {ffln_w + l * 64, 64};
        na.e[s++] = {ffln_b + l * 64, 64};
        na.e[s++] = {fc2_w + (long)l * 4096, 4096};
        na.e[s++] = {fc2_b + l * 64, 64};
        na.e[s++] = {ffln2_w + l * 64, 64};
        na.e[s++] = {ffln2_b + l * 64, 64};
    }
    norms_kernel<<<30, 256, 0, stream>>>(na, nrm);

    final_kernel<<<1, 256, 0, stream>>>(EE, FF, pred_w, rpart, nrm, (float*)d_out);
}

// Round 5
// 838.164 us; speedup vs baseline: 1.8454x; 1.4534x over previous
//
#include <hip/hip_runtime.h>
#include <math.h>

#define BB 512
#define SS 200
#define DDIM 64
#define HD 32
#define LL 2
#define NROWS (BB * SS)   // 102400
#define EPS 1e-8f
#define CC 0.001f
#define GRAM_NB 256

// ---------------- static device buffers (activations) ----------------
__device__ float g_x[NROWS * DDIM];
__device__ float g_qin[NROWS * DDIM];
__device__ float g_q[NROWS * DDIM];
__device__ float g_k[NROWS * DDIM];
__device__ float g_v[NROWS * DDIM];
__device__ float g_ctx[NROWS * DDIM];
__device__ float g_gpart[GRAM_NB * 4096];   // gram per-block partials

// ---------------- helpers ----------------
__device__ __forceinline__ float wave_sum(float v) {
#pragma unroll
    for (int o = 32; o > 0; o >>= 1) v += __shfl_xor(v, o, 64);
    return v;
}
__device__ __forceinline__ float wave_max(float v) {
#pragma unroll
    for (int o = 32; o > 0; o >>= 1) v = fmaxf(v, __shfl_xor(v, o, 64));
    return v;
}

// ---------------- embedding ----------------
__global__ __launch_bounds__(256) void embed_kernel(const int* __restrict__ log_seqs,
                                                    const float* __restrict__ item_emb,
                                                    const float* __restrict__ pos_emb,
                                                    float* __restrict__ x) {
    int tid = blockIdx.x * 256 + threadIdx.x;   // over NROWS*64
    int row = tid >> 6, d = tid & 63;
    int s = row % SS;
    int li = log_seqs[row];
    int poss = li ? (s + 1) : 0;
    x[tid] = item_emb[li * DDIM + d] * 8.0f + pos_emb[poss * DDIM + d];
}

// ---------------- tile staging helpers ----------------
__device__ __forceinline__ void stage_in(const float* __restrict__ G, float (* __restrict__ tile)[68],
                                         int t, long row0) {
#pragma unroll
    for (int rep = 0; rep < 4; ++rep) {
        int idx = t + rep * 256;
        int c = idx >> 4, d4 = (idx & 15) * 4;
        *(float4*)&tile[c][d4] = *(const float4*)&G[(row0 + c) * DDIM + d4];
    }
}

// Stage W (64 out x 64 in, row-major) TRANSPOSED into wt[d][c], via 4x4 block transpose.
__device__ __forceinline__ void stage_wT(const float* __restrict__ Wg, float (* __restrict__ wt)[68], int t) {
    int bi = t & 15, bj = t >> 4;   // bi: c-block, bj: d-block
    float rv[4][4];
#pragma unroll
    for (int e = 0; e < 4; ++e)
        *(float4*)rv[e] = *(const float4*)&Wg[(bi * 4 + e) * DDIM + bj * 4];
#pragma unroll
    for (int e = 0; e < 4; ++e) {
        float4 o;
        o.x = rv[0][e]; o.y = rv[1][e]; o.z = rv[2][e]; o.w = rv[3][e];
        *(float4*)&wt[bj * 4 + e][bi * 4] = o;
    }
}

// acc[i][j] += sum_d A[r0+i][d] * W[d][c0+j]   (W stored transposed: wt[d][c])
__device__ __forceinline__ void gemm_tile(const float (* __restrict__ A)[68],
                                          const float (* __restrict__ W)[68],
                                          int r0, int c0, float acc[4][4]) {
#pragma unroll
    for (int d = 0; d < 64; d += 4) {
        float4 a[4], wv[4];
#pragma unroll
        for (int i = 0; i < 4; ++i) a[i] = *(const float4*)&A[r0 + i][d];
#pragma unroll
        for (int tt = 0; tt < 4; ++tt) wv[tt] = *(const float4*)&W[d + tt][c0];
#pragma unroll
        for (int i = 0; i < 4; ++i) {
            float av[4] = {a[i].x, a[i].y, a[i].z, a[i].w};
#pragma unroll
            for (int tt = 0; tt < 4; ++tt) {
                acc[i][0] += av[tt] * wv[tt].x;
                acc[i][1] += av[tt] * wv[tt].y;
                acc[i][2] += av[tt] * wv[tt].z;
                acc[i][3] += av[tt] * wv[tt].w;
            }
        }
    }
}

// LayerNorm rows of src -> dst (thread t owns row t>>2, 16-col chunk (t&3)*16).
__device__ __forceinline__ void ln_rows(const float (* __restrict__ src)[68], float (* __restrict__ dst)[68],
                                        const float* __restrict__ w_s, const float* __restrict__ b_s,
                                        int t, float* __restrict__ save) {
    int rr = t >> 2, qd = (t & 3) * 16;
    float4 v[4];
#pragma unroll
    for (int g = 0; g < 4; ++g) v[g] = *(const float4*)&src[rr][qd + g * 4];
    float s1 = 0.f, s2 = 0.f;
#pragma unroll
    for (int g = 0; g < 4; ++g) {
        s1 += (v[g].x + v[g].y) + (v[g].z + v[g].w);
        s2 += (v[g].x * v[g].x + v[g].y * v[g].y) + (v[g].z * v[g].z + v[g].w * v[g].w);
    }
    s1 += __shfl_xor(s1, 1, 64); s1 += __shfl_xor(s1, 2, 64);
    s2 += __shfl_xor(s2, 1, 64); s2 += __shfl_xor(s2, 2, 64);
    float m = s1 * (1.f / 64.f);
    float var = s2 * (1.f / 64.f) - m * m;
    float rs = rsqrtf(var + EPS);
#pragma unroll
    for (int g = 0; g < 4; ++g) {
        float4 w4 = *(const float4*)&w_s[qd + g * 4];
        float4 b4 = *(const float4*)&b_s[qd + g * 4];
        float4 o;
        o.x = (v[g].x - m) * rs * w4.x + b4.x;
        o.y = (v[g].y - m) * rs * w4.y + b4.y;
        o.z = (v[g].z - m) * rs * w4.z + b4.z;
        o.w = (v[g].w - m) * rs * w4.w + b4.w;
        *(float4*)&dst[rr][qd + g * 4] = o;
        if (save) *(float4*)&save[rr * DDIM + qd + g * 4] = o;
    }
}

// Dual LayerNorm: a := LN1(a), b := LN2(a_old)
__device__ __forceinline__ void ln_rows2(float (* __restrict__ a)[68], float (* __restrict__ b)[68],
                                         const float* __restrict__ w1, const float* __restrict__ b1,
                                         const float* __restrict__ w2, const float* __restrict__ b2, int t) {
    int rr = t >> 2, qd = (t & 3) * 16;
    float4 v[4];
#pragma unroll
    for (int g = 0; g < 4; ++g) v[g] = *(const float4*)&a[rr][qd + g * 4];
    float s1 = 0.f, s2 = 0.f;
#pragma unroll
    for (int g = 0; g < 4; ++g) {
        s1 += (v[g].x + v[g].y) + (v[g].z + v[g].w);
        s2 += (v[g].x * v[g].x + v[g].y * v[g].y) + (v[g].z * v[g].z + v[g].w * v[g].w);
    }
    s1 += __shfl_xor(s1, 1, 64); s1 += __shfl_xor(s1, 2, 64);
    s2 += __shfl_xor(s2, 1, 64); s2 += __shfl_xor(s2, 2, 64);
    float m = s1 * (1.f / 64.f);
    float var = s2 * (1.f / 64.f) - m * m;
    float rs = rsqrtf(var + EPS);
#pragma unroll
    for (int g = 0; g < 4; ++g) {
        float4 w14 = *(const float4*)&w1[qd + g * 4];
        float4 b14 = *(const float4*)&b1[qd + g * 4];
        float4 w24 = *(const float4*)&w2[qd + g * 4];
        float4 b24 = *(const float4*)&b2[qd + g * 4];
        float nx = (v[g].x - m) * rs, ny = (v[g].y - m) * rs, nz = (v[g].z - m) * rs, nw = (v[g].w - m) * rs;
        float4 o1, o2;
        o1.x = nx * w14.x + b14.x; o1.y = ny * w14.y + b14.y; o1.z = nz * w14.z + b14.z; o1.w = nw * w14.w + b14.w;
        o2.x = nx * w24.x + b24.x; o2.y = ny * w24.y + b24.y; o2.z = nz * w24.z + b24.z; o2.w = nw * w24.w + b24.w;
        *(float4*)&a[rr][qd + g * 4] = o1;
        *(float4*)&b[rr][qd + g * 4] = o2;
    }
}

// ---------------- fused QKV ----------------
__global__ __launch_bounds__(256) void qkv_fused(const float* __restrict__ x,
                                                 const float* __restrict__ Wqkv,
                                                 const float* __restrict__ Bqkv,
                                                 const float* __restrict__ lnw,
                                                 const float* __restrict__ lnb,
                                                 float* __restrict__ qin,
                                                 float* __restrict__ qo,
                                                 float* __restrict__ ko,
                                                 float* __restrict__ vo) {
    __shared__ float A[64][68], B[64][68], W[64][68];
    __shared__ float lw[64], lb[64];
    int t = threadIdx.x;
    long row0 = (long)blockIdx.x * 64;
    stage_in(x, A, t, row0);
    stage_wT(Wqkv, W, t);
    if (t < 64) { lw[t] = lnw[t]; lb[t] = lnb[t]; }
    __syncthreads();
    ln_rows(A, B, lw, lb, t, qin + row0 * DDIM);
    __syncthreads();
    int tx = t & 15, ty = t >> 4, r0 = ty * 4, c0 = tx * 4;
    {
        float acc[4][4] = {};
        gemm_tile(B, W, r0, c0, acc);
        float4 b4 = *(const float4*)&Bqkv[c0];
        float bv[4] = {b4.x, b4.y, b4.z, b4.w};
#pragma unroll
        for (int i = 0; i < 4; ++i) {
            float4 o; o.x = acc[i][0] + bv[0]; o.y = acc[i][1] + bv[1]; o.z = acc[i][2] + bv[2]; o.w = acc[i][3] + bv[3];
            *(float4*)&qo[(row0 + r0 + i) * DDIM + c0] = o;
        }
    }
    __syncthreads();
    stage_wT(Wqkv + 4096, W, t);
    __syncthreads();
    {
        float acc[4][4] = {};
        gemm_tile(A, W, r0, c0, acc);
        float4 b4 = *(const float4*)&Bqkv[64 + c0];
        float bv[4] = {b4.x, b4.y, b4.z, b4.w};
#pragma unroll
        for (int i = 0; i < 4; ++i) {
            float4 o; o.x = acc[i][0] + bv[0]; o.y = acc[i][1] + bv[1]; o.z = acc[i][2] + bv[2]; o.w = acc[i][3] + bv[3];
            *(float4*)&ko[(row0 + r0 + i) * DDIM + c0] = o;
        }
    }
    __syncthreads();
    stage_wT(Wqkv + 8192, W, t);
    __syncthreads();
    {
        float acc[4][4] = {};
        gemm_tile(A, W, r0, c0, acc);
        float4 b4 = *(const float4*)&Bqkv[128 + c0];
        float bv[4] = {b4.x, b4.y, b4.z, b4.w};
#pragma unroll
        for (int i = 0; i < 4; ++i) {
            float4 o; o.x = acc[i][0] + bv[0]; o.y = acc[i][1] + bv[1]; o.z = acc[i][2] + bv[2]; o.w = acc[i][3] + bv[3];
            *(float4*)&vo[(row0 + r0 + i) * DDIM + c0] = o;
        }
    }
}

// ---------------- fused out-proj + FFN ----------------
__global__ __launch_bounds__(256) void ffn_fused(const float* __restrict__ ctx,
                                                 const float* __restrict__ qin,
                                                 const float* __restrict__ Wo, const float* __restrict__ bo,
                                                 const float* __restrict__ W1, const float* __restrict__ b1,
                                                 const float* __restrict__ W2, const float* __restrict__ b2,
                                                 const float* __restrict__ l1w, const float* __restrict__ l1b,
                                                 const float* __restrict__ l2w, const float* __restrict__ l2b,
                                                 float* __restrict__ xout) {
    __shared__ float A[64][68], B[64][68], W[64][68];
    __shared__ float w1s[64], b1s[64], w2s[64], b2s[64];
    int t = threadIdx.x;
    long row0 = (long)blockIdx.x * 64;
    stage_in(ctx, A, t, row0);
    stage_in(qin, B, t, row0);
    stage_wT(Wo, W, t);
    if (t < 64) { w1s[t] = l1w[t]; b1s[t] = l1b[t]; w2s[t] = l2w[t]; b2s[t] = l2b[t]; }
    __syncthreads();
    int tx = t & 15, ty = t >> 4, r0 = ty * 4, c0 = tx * 4;
    float x1[4][4] = {};
    gemm_tile(A, W, r0, c0, x1);
    {
        float4 b4 = *(const float4*)&bo[c0];
        float bv[4] = {b4.x, b4.y, b4.z, b4.w};
#pragma unroll
        for (int i = 0; i < 4; ++i)
#pragma unroll
            for (int j = 0; j < 4; ++j) x1[i][j] += bv[j] + B[r0 + i][c0 + j];
    }
    __syncthreads();
#pragma unroll
    for (int i = 0; i < 4; ++i) {
        float4 o; o.x = x1[i][0]; o.y = x1[i][1]; o.z = x1[i][2]; o.w = x1[i][3];
        *(float4*)&A[r0 + i][c0] = o;
    }
    __syncthreads();
    ln_rows2(A, B, w1s, b1s, w2s, b2s, t);
    stage_wT(W1, W, t);
    __syncthreads();
    float h[4][4] = {};
    gemm_tile(A, W, r0, c0, h);
    {
        float4 b4 = *(const float4*)&b1[c0];
        float bv[4] = {b4.x, b4.y, b4.z, b4.w};
#pragma unroll
        for (int i = 0; i < 4; ++i)
#pragma unroll
            for (int j = 0; j < 4; ++j) h[i][j] = fmaxf(h[i][j] + bv[j], 0.f);
    }
    __syncthreads();
#pragma unroll
    for (int i = 0; i < 4; ++i) {
        float4 o; o.x = h[i][0]; o.y = h[i][1]; o.z = h[i][2]; o.w = h[i][3];
        *(float4*)&A[r0 + i][c0] = o;
    }
    stage_wT(W2, W, t);
    __syncthreads();
    float o3[4][4] = {};
    gemm_tile(A, W, r0, c0, o3);
    {
        float4 b4 = *(const float4*)&b2[c0];
        float bv[4] = {b4.x, b4.y, b4.z, b4.w};
#pragma unroll
        for (int i = 0; i < 4; ++i) {
            float4 o;
            o.x = o3[i][0] + bv[0] + B[r0 + i][c0 + 0];
            o.y = o3[i][1] + bv[1] + B[r0 + i][c0 + 1];
            o.z = o3[i][2] + bv[2] + B[r0 + i][c0 + 2];
            o.w = o3[i][3] + bv[3] + B[r0 + i][c0 + 3];
            *(float4*)&xout[(row0 + r0 + i) * DDIM + c0] = o;
        }
    }
}

// ---------------- causal attention, one block per (b, head), 8 waves ----------------
__global__ __launch_bounds__(512) void attn_kernel(const float* __restrict__ q,
                                                   const float* __restrict__ k,
                                                   const float* __restrict__ v,
                                                   float* __restrict__ ctx) {
    __shared__ float K4[SS * 32];     // [(kk*8 + (dq^(kk&7)))*4 + e]
    __shared__ float V_s[SS * 32];    // [kk*32 + d]
    __shared__ float A_s[8][SS];
    int b = blockIdx.x >> 1, h = blockIdx.x & 1;
    int t = threadIdx.x;
    const long base = (long)b * (SS * DDIM) + h * HD;
    for (int i = t; i < SS * 8; i += 512) {
        int kk = i >> 3, dq = i & 7;
        float4 k4 = *(const float4*)&k[base + kk * DDIM + dq * 4];
        *(float4*)&K4[(kk * 8 + (dq ^ (kk & 7))) * 4] = k4;
    }
    for (int i = t; i < SS * HD; i += 512) {
        int kk = i >> 5, d = i & 31;
        V_s[kk * 32 + d] = v[base + kk * DDIM + d];
    }
    __syncthreads();
    int w = t >> 6, lane = t & 63;
    const float scale = 0.17677669529663687f;   // 1/sqrt(32)
    const float* Aw = A_s[w];
    for (int r = w; r < SS; r += 8) {
        float4 qv4[8];
#pragma unroll
        for (int dq = 0; dq < 8; ++dq) qv4[dq] = *(const float4*)&q[base + r * DDIM + dq * 4];
        int ncb = (r >> 6) + 1;
        float sc[4];
        float m = -1e30f;
        for (int c = 0; c < ncb; ++c) {
            int kk = lane + c * 64;
            sc[c] = -1e30f;
            if (kk <= r) {
                int sw = kk & 7;
                float d0 = 0.f, d1 = 0.f, d2 = 0.f, d3 = 0.f;
#pragma unroll
                for (int dq = 0; dq < 8; ++dq) {
                    float4 k4 = *(const float4*)&K4[(kk * 8 + (dq ^ sw)) * 4];
                    d0 += qv4[dq].x * k4.x;
                    d1 += qv4[dq].y * k4.y;
                    d2 += qv4[dq].z * k4.z;
                    d3 += qv4[dq].w * k4.w;
                }
                sc[c] = ((d0 + d1) + (d2 + d3)) * scale;
            }
            m = fmaxf(m, sc[c]);
        }
        m = wave_max(m);
        float sum = 0.f;
        for (int c = 0; c < ncb; ++c) {
            int kk = lane + c * 64;
            if (kk <= r) { sc[c] = __expf(sc[c] - m); sum += sc[c]; }
        }
        sum = wave_sum(sum);
        float inv = 1.f / sum;
        for (int c = 0; c < ncb; ++c) {
            int kk = lane + c * 64;
            if (kk <= r) A_s[w][kk] = sc[c] * inv;
        }
        int half = lane >> 5, d = lane & 31;
        float a0 = 0.f, a1 = 0.f, a2 = 0.f, a3 = 0.f;
        int kk = half;
        for (; kk + 6 <= r; kk += 8) {
            a0 += Aw[kk]     * V_s[kk * 32 + d];
            a1 += Aw[kk + 2] * V_s[(kk + 2) * 32 + d];
            a2 += Aw[kk + 4] * V_s[(kk + 4) * 32 + d];
            a3 += Aw[kk + 6] * V_s[(kk + 6) * 32 + d];
        }
        for (; kk <= r; kk += 2) a0 += Aw[kk] * V_s[kk * 32 + d];
        float acc = (a0 + a1) + (a2 + a3);
        acc += __shfl_xor(acc, 32, 64);
        if (half == 0) ctx[base + r * DDIM + d] = acc;
    }
}

// ---------------- Gram matrix partials: part[b][i*64+j] = sum_r A[r,i]*A[r,j] ----------------
// No global atomics: each block owns a 4096-float slab; gram_reduce sums them.
__global__ __launch_bounds__(256) void gram_kernel(const float* __restrict__ A, int nrows,
                                                   float* __restrict__ part) {
    __shared__ float rows[16][64];
    int t = threadIdx.x;
    int i = t >> 2;            // 0..63
    int jb = (t & 3) * 16;     // 0/16/32/48
    float acc[16] = {};
    for (long base = (long)blockIdx.x * 16; base < nrows; base += (long)GRAM_NB * 16) {
        {
            int rr = t >> 4, d4 = (t & 15) * 4;
            long gr = base + rr;
            float4 vv = make_float4(0.f, 0.f, 0.f, 0.f);
            if (gr < nrows) vv = *(const float4*)&A[gr * DDIM + d4];
            *(float4*)&rows[rr][d4] = vv;
        }
        __syncthreads();
#pragma unroll
        for (int rr = 0; rr < 16; ++rr) {
            float ai = rows[rr][i];
            float4 r0 = *(const float4*)&rows[rr][jb];
            float4 r1 = *(const float4*)&rows[rr][jb + 4];
            float4 r2 = *(const float4*)&rows[rr][jb + 8];
            float4 r3 = *(const float4*)&rows[rr][jb + 12];
            acc[0] += ai * r0.x; acc[1] += ai * r0.y; acc[2] += ai * r0.z; acc[3] += ai * r0.w;
            acc[4] += ai * r1.x; acc[5] += ai * r1.y; acc[6] += ai * r1.z; acc[7] += ai * r1.w;
            acc[8] += ai * r2.x; acc[9] += ai * r2.y; acc[10] += ai * r2.z; acc[11] += ai * r2.w;
            acc[12] += ai * r3.x; acc[13] += ai * r3.y; acc[14] += ai * r3.z; acc[15] += ai * r3.w;
        }
        __syncthreads();
    }
    float* slab = part + (long)blockIdx.x * 4096 + i * 64 + jb;
#pragma unroll
    for (int g = 0; g < 4; ++g) {
        float4 o; o.x = acc[g * 4]; o.y = acc[g * 4 + 1]; o.z = acc[g * 4 + 2]; o.w = acc[g * 4 + 3];
        *(float4*)&slab[g * 4] = o;
    }
}

// out[p] = sum_b part[b*4096+p]
__global__ __launch_bounds__(256) void gram_reduce(const float* __restrict__ part,
                                                   float* __restrict__ out) {
    int p = blockIdx.x * 256 + threadIdx.x;   // 16 blocks
    float s = 0.f;
    for (int b = 0; b < GRAM_NB; ++b) s += part[(long)b * 4096 + p];
    out[p] = s;
}

// ---------------- right(): per-block partial sums of (1-C)ps^2 - 2ps ----------------
__global__ __launch_bounds__(256) void right_kernel(const float* __restrict__ x,
                                                    const float* __restrict__ item_emb,
                                                    const int* __restrict__ pos_seqs,
                                                    const float* __restrict__ pred_w,
                                                    float* __restrict__ rpart) {
    __shared__ float p_s[64];
    __shared__ float red[4];
    int t = threadIdx.x;
    if (t < 64) p_s[t] = pred_w[t];
    __syncthreads();
    int w = t >> 6, lane = t & 63;
    float local = 0.f;
    for (long row = (long)blockIdx.x * 4 + w; row < NROWS; row += (long)gridDim.x * 4) {
        int pi = pos_seqs[row];
        float val = x[row * DDIM + lane] * item_emb[(long)pi * DDIM + lane] * p_s[lane];
        float ps = wave_sum(val);           // lane-uniform
        local += (1.0f - CC) * ps * ps - 2.0f * ps;   // identical on all 64 lanes
    }
    if (lane == 0) red[w] = local;          // take lane 0's copy — no scaling
    __syncthreads();
    if (t == 0) rpart[blockIdx.x] = red[0] + red[1] + red[2] + red[3];
}

// ---------------- per-parameter sum-of-squares ----------------
struct NormEntry { const float* p; int n; };
struct NormArgs { NormEntry e[30]; };

__global__ __launch_bounds__(256) void norms_kernel(NormArgs args, float* __restrict__ norms) {
    __shared__ float red[256];
    NormEntry en = args.e[blockIdx.x];
    float s = 0.f;
    for (int i = threadIdx.x; i < en.n; i += 256) { float v = en.p[i]; s += v * v; }
    red[threadIdx.x] = s;
    for (int o = 128; o > 0; o >>= 1) {
        __syncthreads();
        if (threadIdx.x < o) red[threadIdx.x] += red[threadIdx.x + o];
    }
    __syncthreads();
    if (threadIdx.x == 0) norms[blockIdx.x] = red[0];
}

// ---------------- final scalar ----------------
__global__ __launch_bounds__(256) void final_kernel(const float* __restrict__ EE,
                                                    const float* __restrict__ FF,
                                                    const float* __restrict__ pred_w,
                                                    const float* __restrict__ rpart,
                                                    const float* __restrict__ norms,
                                                    float* __restrict__ out) {
    __shared__ float p_s[64];
    __shared__ float redL[256];
    __shared__ float redT[256];
    __shared__ float redR[256];
    int t = threadIdx.x;
    if (t < 64) p_s[t] = pred_w[t];
    __syncthreads();
    float lf = 0.f, tr = 0.f, rs = 0.f;
    for (int p = t; p < 4096; p += 256) {
        int i = p >> 6, j = p & 63;
        float ee = EE[p];
        lf += FF[p] * ee * p_s[i] * p_s[j];
        if (i == j) tr += ee;
    }
    for (int i = t; i < 1024; i += 256) rs += rpart[i];
    redL[t] = lf; redT[t] = tr; redR[t] = rs;
    for (int o = 128; o > 0; o >>= 1) {
        __syncthreads();
        if (t < o) { redL[t] += redL[t + o]; redT[t] += redT[t + o]; redR[t] += redR[t + o]; }
    }
    __syncthreads();
    if (t == 0) {
        float reg = sqrtf(redT[0]);   // ||item_emb||_F = sqrt(trace(EE))
        for (int s = 0; s < 30; ++s) reg += sqrtf(norms[s]);
        out[0] = CC * redL[0] + redR[0] + 0.1f * reg;
    }
}

// ---------------- host ----------------
struct DevPtrs { float *x, *qin, *q, *k, *v, *ctx, *gpart; };

static DevPtrs fetch_ptrs() {
    DevPtrs p;
    (void)hipGetSymbolAddress((void**)&p.x,    HIP_SYMBOL(g_x));
    (void)hipGetSymbolAddress((void**)&p.qin,  HIP_SYMBOL(g_qin));
    (void)hipGetSymbolAddress((void**)&p.q,    HIP_SYMBOL(g_q));
    (void)hipGetSymbolAddress((void**)&p.k,    HIP_SYMBOL(g_k));
    (void)hipGetSymbolAddress((void**)&p.v,    HIP_SYMBOL(g_v));
    (void)hipGetSymbolAddress((void**)&p.ctx,  HIP_SYMBOL(g_ctx));
    (void)hipGetSymbolAddress((void**)&p.gpart,HIP_SYMBOL(g_gpart));
    return p;
}

extern "C" void kernel_launch(void* const* d_in, const int* in_sizes, int n_in,
                              void* d_out, int out_size, void* d_ws, size_t ws_size,
                              hipStream_t stream) {
    const int*   log_seqs = (const int*)d_in[1];
    const int*   pos_seqs = (const int*)d_in[2];
    const float* item_emb = (const float*)d_in[3];
    const float* pos_emb  = (const float*)d_in[4];
    const float* pred_w   = (const float*)d_in[5];
    const float* ln_w     = (const float*)d_in[6];
    const float* ln_b     = (const float*)d_in[7];
    const float* qkv_w    = (const float*)d_in[8];
    const float* qkv_b    = (const float*)d_in[9];
    const float* out_w    = (const float*)d_in[10];
    const float* out_b    = (const float*)d_in[11];
    const float* fc1_w    = (const float*)d_in[12];
    const float* fc1_b    = (const float*)d_in[13];
    const float* ffln_w   = (const float*)d_in[14];
    const float* ffln_b   = (const float*)d_in[15];
    const float* fc2_w    = (const float*)d_in[16];
    const float* fc2_b    = (const float*)d_in[17];
    const float* ffln2_w  = (const float*)d_in[18];
    const float* ffln2_b  = (const float*)d_in[19];

    static DevPtrs P = fetch_ptrs();   // first call is the uncaptured correctness call

    float* ws    = (float*)d_ws;
    float* rpart = ws;            // 1024
    float* nrm   = ws + 1024;     // 30
    float* EE    = ws + 2048;     // 4096
    float* FF    = ws + 6144;     // 4096

    embed_kernel<<<NROWS * DDIM / 256, 256, 0, stream>>>(log_seqs, item_emb, pos_emb, P.x);

    const int GEMM_GRID = NROWS / 64;   // 1600

    for (int l = 0; l < LL; ++l) {
        const float* Wqkv = qkv_w + (long)l * 3 * 64 * 64;
        const float* Bqkv = qkv_b + (long)l * 192;
        qkv_fused<<<GEMM_GRID, 256, 0, stream>>>(
            P.x, Wqkv, Bqkv, ln_w + l * 64, ln_b + l * 64, P.qin, P.q, P.k, P.v);
        attn_kernel<<<BB * 2, 512, 0, stream>>>(P.q, P.k, P.v, P.ctx);
        ffn_fused<<<GEMM_GRID, 256, 0, stream>>>(
            P.ctx, P.qin,
            out_w + (long)l * 4096, out_b + l * 64,
            fc1_w + (long)l * 4096, fc1_b + l * 64,
            fc2_w + (long)l * 4096, fc2_b + l * 64,
            ffln_w + l * 64, ffln_b + l * 64,
            ffln2_w + l * 64, ffln2_b + l * 64,
            P.x);
    }

    gram_kernel<<<GRAM_NB, 256, 0, stream>>>(item_emb, 100001, P.gpart);
    gram_reduce<<<16, 256, 0, stream>>>(P.gpart, EE);
    gram_kernel<<<GRAM_NB, 256, 0, stream>>>(P.x, NROWS, P.gpart);
    gram_reduce<<<16, 256, 0, stream>>>(P.gpart, FF);
    right_kernel<<<1024, 256, 0, stream>>>(P.x, item_emb, pos_seqs, pred_w, rpart);

    NormArgs na;
    int s = 0;
    na.e[s++] = {pos_emb, (SS + 1) * DDIM};
    na.e[s++] = {pred_w, DDIM};
    for (int l = 0; l < LL; ++l) {
        na.e[s++] = {ln_w + l * 64, 64};
        na.e[s++] = {ln_b + l * 64, 64};
        na.e[s++] = {qkv_w + (long)l * 12288, 12288};
        na.e[s++] = {qkv_b + (long)l * 192, 192};
        na.e[s++] = {out_w + (long)l * 4096, 4096};
        na.e[s++] = {out_b + l * 64, 64};
        na.e[s++] = {fc1_w + (long)l * 4096, 4096};
        na.e[s++] = {fc1_b + l * 64, 64};
        na.e[s++] = {ffln_w + l * 64, 64};
        na.e[s++] = {ffln_b + l * 64, 64};
        na.e[s++] = {fc2_w + (long)l * 4096, 4096};
        na.e[s++] = {fc2_b + l * 64, 64};
        na.e[s++] = {ffln2_w + l * 64, 64};
        na.e[s++] = {ffln2_b + l * 64, 64};
    }
    norms_kernel<<<30, 256, 0, stream>>>(na, nrm);

    final_kernel<<<1, 256, 0, stream>>>(EE, FF, pred_w, rpart, nrm, (float*)d_out);
}

// Round 6
// 755.168 us; speedup vs baseline: 2.0483x; 1.1099x over previous
//
#include <hip/hip_runtime.h>
#include <math.h>

#define BB 512
#define SS 200
#define DDIM 64
#define HD 32
#define LL 2
#define NROWS (BB * SS)   // 102400
#define EPS 1e-8f
#define CC 0.001f
#define GRAM_NB 256

// ---------------- static device buffers (activations) ----------------
__device__ float g_x[NROWS * DDIM];
__device__ float g_qin[NROWS * DDIM];
__device__ float g_q[NROWS * DDIM];
__device__ float g_k[NROWS * DDIM];
__device__ float g_v[NROWS * DDIM];
__device__ float g_ctx[NROWS * DDIM];
__device__ float g_gpart[GRAM_NB * 4096];   // gram per-block partials

// ---------------- helpers ----------------
__device__ __forceinline__ float wave_sum(float v) {
#pragma unroll
    for (int o = 32; o > 0; o >>= 1) v += __shfl_xor(v, o, 64);
    return v;
}
__device__ __forceinline__ float wave_max(float v) {
#pragma unroll
    for (int o = 32; o > 0; o >>= 1) v = fmaxf(v, __shfl_xor(v, o, 64));
    return v;
}

// ---------------- embedding ----------------
__global__ __launch_bounds__(256) void embed_kernel(const int* __restrict__ log_seqs,
                                                    const float* __restrict__ item_emb,
                                                    const float* __restrict__ pos_emb,
                                                    float* __restrict__ x) {
    int tid = blockIdx.x * 256 + threadIdx.x;   // over NROWS*64
    int row = tid >> 6, d = tid & 63;
    int s = row % SS;
    int li = log_seqs[row];
    int poss = li ? (s + 1) : 0;
    x[tid] = item_emb[li * DDIM + d] * 8.0f + pos_emb[poss * DDIM + d];
}

// ---------------- tile staging helpers ----------------
__device__ __forceinline__ void stage_in(const float* __restrict__ G, float (* __restrict__ tile)[68],
                                         int t, long row0) {
#pragma unroll
    for (int rep = 0; rep < 4; ++rep) {
        int idx = t + rep * 256;
        int c = idx >> 4, d4 = (idx & 15) * 4;
        *(float4*)&tile[c][d4] = *(const float4*)&G[(row0 + c) * DDIM + d4];
    }
}

// Stage W (64 out x 64 in, row-major) TRANSPOSED into wt[d][c], via 4x4 block transpose.
__device__ __forceinline__ void stage_wT(const float* __restrict__ Wg, float (* __restrict__ wt)[68], int t) {
    int bi = t & 15, bj = t >> 4;   // bi: c-block, bj: d-block
    float rv[4][4];
#pragma unroll
    for (int e = 0; e < 4; ++e)
        *(float4*)rv[e] = *(const float4*)&Wg[(bi * 4 + e) * DDIM + bj * 4];
#pragma unroll
    for (int e = 0; e < 4; ++e) {
        float4 o;
        o.x = rv[0][e]; o.y = rv[1][e]; o.z = rv[2][e]; o.w = rv[3][e];
        *(float4*)&wt[bj * 4 + e][bi * 4] = o;
    }
}

// acc[i][j] += sum_d A[r0+i][d] * W[d][c0+j]   (W stored transposed: wt[d][c])
__device__ __forceinline__ void gemm_tile(const float (* __restrict__ A)[68],
                                          const float (* __restrict__ W)[68],
                                          int r0, int c0, float acc[4][4]) {
#pragma unroll
    for (int d = 0; d < 64; d += 4) {
        float4 a[4], wv[4];
#pragma unroll
        for (int i = 0; i < 4; ++i) a[i] = *(const float4*)&A[r0 + i][d];
#pragma unroll
        for (int tt = 0; tt < 4; ++tt) wv[tt] = *(const float4*)&W[d + tt][c0];
#pragma unroll
        for (int i = 0; i < 4; ++i) {
            float av[4] = {a[i].x, a[i].y, a[i].z, a[i].w};
#pragma unroll
            for (int tt = 0; tt < 4; ++tt) {
                acc[i][0] += av[tt] * wv[tt].x;
                acc[i][1] += av[tt] * wv[tt].y;
                acc[i][2] += av[tt] * wv[tt].z;
                acc[i][3] += av[tt] * wv[tt].w;
            }
        }
    }
}

// LayerNorm rows of src -> dst (thread t owns row t>>2, 16-col chunk (t&3)*16).
__device__ __forceinline__ void ln_rows(const float (* __restrict__ src)[68], float (* __restrict__ dst)[68],
                                        const float* __restrict__ w_s, const float* __restrict__ b_s,
                                        int t, float* __restrict__ save) {
    int rr = t >> 2, qd = (t & 3) * 16;
    float4 v[4];
#pragma unroll
    for (int g = 0; g < 4; ++g) v[g] = *(const float4*)&src[rr][qd + g * 4];
    float s1 = 0.f, s2 = 0.f;
#pragma unroll
    for (int g = 0; g < 4; ++g) {
        s1 += (v[g].x + v[g].y) + (v[g].z + v[g].w);
        s2 += (v[g].x * v[g].x + v[g].y * v[g].y) + (v[g].z * v[g].z + v[g].w * v[g].w);
    }
    s1 += __shfl_xor(s1, 1, 64); s1 += __shfl_xor(s1, 2, 64);
    s2 += __shfl_xor(s2, 1, 64); s2 += __shfl_xor(s2, 2, 64);
    float m = s1 * (1.f / 64.f);
    float var = s2 * (1.f / 64.f) - m * m;
    float rs = rsqrtf(var + EPS);
#pragma unroll
    for (int g = 0; g < 4; ++g) {
        float4 w4 = *(const float4*)&w_s[qd + g * 4];
        float4 b4 = *(const float4*)&b_s[qd + g * 4];
        float4 o;
        o.x = (v[g].x - m) * rs * w4.x + b4.x;
        o.y = (v[g].y - m) * rs * w4.y + b4.y;
        o.z = (v[g].z - m) * rs * w4.z + b4.z;
        o.w = (v[g].w - m) * rs * w4.w + b4.w;
        *(float4*)&dst[rr][qd + g * 4] = o;
        if (save) *(float4*)&save[rr * DDIM + qd + g * 4] = o;
    }
}

// Dual LayerNorm: a := LN1(a), b := LN2(a_old)
__device__ __forceinline__ void ln_rows2(float (* __restrict__ a)[68], float (* __restrict__ b)[68],
                                         const float* __restrict__ w1, const float* __restrict__ b1,
                                         const float* __restrict__ w2, const float* __restrict__ b2, int t) {
    int rr = t >> 2, qd = (t & 3) * 16;
    float4 v[4];
#pragma unroll
    for (int g = 0; g < 4; ++g) v[g] = *(const float4*)&a[rr][qd + g * 4];
    float s1 = 0.f, s2 = 0.f;
#pragma unroll
    for (int g = 0; g < 4; ++g) {
        s1 += (v[g].x + v[g].y) + (v[g].z + v[g].w);
        s2 += (v[g].x * v[g].x + v[g].y * v[g].y) + (v[g].z * v[g].z + v[g].w * v[g].w);
    }
    s1 += __shfl_xor(s1, 1, 64); s1 += __shfl_xor(s1, 2, 64);
    s2 += __shfl_xor(s2, 1, 64); s2 += __shfl_xor(s2, 2, 64);
    float m = s1 * (1.f / 64.f);
    float var = s2 * (1.f / 64.f) - m * m;
    float rs = rsqrtf(var + EPS);
#pragma unroll
    for (int g = 0; g < 4; ++g) {
        float4 w14 = *(const float4*)&w1[qd + g * 4];
        float4 b14 = *(const float4*)&b1[qd + g * 4];
        float4 w24 = *(const float4*)&w2[qd + g * 4];
        float4 b24 = *(const float4*)&b2[qd + g * 4];
        float nx = (v[g].x - m) * rs, ny = (v[g].y - m) * rs, nz = (v[g].z - m) * rs, nw = (v[g].w - m) * rs;
        float4 o1, o2;
        o1.x = nx * w14.x + b14.x; o1.y = ny * w14.y + b14.y; o1.z = nz * w14.z + b14.z; o1.w = nw * w14.w + b14.w;
        o2.x = nx * w24.x + b24.x; o2.y = ny * w24.y + b24.y; o2.z = nz * w24.z + b24.z; o2.w = nw * w24.w + b24.w;
        *(float4*)&a[rr][qd + g * 4] = o1;
        *(float4*)&b[rr][qd + g * 4] = o2;
    }
}

// ---------------- fused QKV ----------------
__global__ __launch_bounds__(256) void qkv_fused(const float* __restrict__ x,
                                                 const float* __restrict__ Wqkv,
                                                 const float* __restrict__ Bqkv,
                                                 const float* __restrict__ lnw,
                                                 const float* __restrict__ lnb,
                                                 float* __restrict__ qin,
                                                 float* __restrict__ qo,
                                                 float* __restrict__ ko,
                                                 float* __restrict__ vo) {
    __shared__ float A[64][68], B[64][68], W[64][68];
    __shared__ float lw[64], lb[64];
    int t = threadIdx.x;
    long row0 = (long)blockIdx.x * 64;
    stage_in(x, A, t, row0);
    stage_wT(Wqkv, W, t);
    if (t < 64) { lw[t] = lnw[t]; lb[t] = lnb[t]; }
    __syncthreads();
    ln_rows(A, B, lw, lb, t, qin + row0 * DDIM);
    __syncthreads();
    int tx = t & 15, ty = t >> 4, r0 = ty * 4, c0 = tx * 4;
    {
        float acc[4][4] = {};
        gemm_tile(B, W, r0, c0, acc);
        float4 b4 = *(const float4*)&Bqkv[c0];
        float bv[4] = {b4.x, b4.y, b4.z, b4.w};
#pragma unroll
        for (int i = 0; i < 4; ++i) {
            float4 o; o.x = acc[i][0] + bv[0]; o.y = acc[i][1] + bv[1]; o.z = acc[i][2] + bv[2]; o.w = acc[i][3] + bv[3];
            *(float4*)&qo[(row0 + r0 + i) * DDIM + c0] = o;
        }
    }
    __syncthreads();
    stage_wT(Wqkv + 4096, W, t);
    __syncthreads();
    {
        float acc[4][4] = {};
        gemm_tile(A, W, r0, c0, acc);
        float4 b4 = *(const float4*)&Bqkv[64 + c0];
        float bv[4] = {b4.x, b4.y, b4.z, b4.w};
#pragma unroll
        for (int i = 0; i < 4; ++i) {
            float4 o; o.x = acc[i][0] + bv[0]; o.y = acc[i][1] + bv[1]; o.z = acc[i][2] + bv[2]; o.w = acc[i][3] + bv[3];
            *(float4*)&ko[(row0 + r0 + i) * DDIM + c0] = o;
        }
    }
    __syncthreads();
    stage_wT(Wqkv + 8192, W, t);
    __syncthreads();
    {
        float acc[4][4] = {};
        gemm_tile(A, W, r0, c0, acc);
        float4 b4 = *(const float4*)&Bqkv[128 + c0];
        float bv[4] = {b4.x, b4.y, b4.z, b4.w};
#pragma unroll
        for (int i = 0; i < 4; ++i) {
            float4 o; o.x = acc[i][0] + bv[0]; o.y = acc[i][1] + bv[1]; o.z = acc[i][2] + bv[2]; o.w = acc[i][3] + bv[3];
            *(float4*)&vo[(row0 + r0 + i) * DDIM + c0] = o;
        }
    }
}

// ---------------- fused out-proj + FFN ----------------
__global__ __launch_bounds__(256) void ffn_fused(const float* __restrict__ ctx,
                                                 const float* __restrict__ qin,
                                                 const float* __restrict__ Wo, const float* __restrict__ bo,
                                                 const float* __restrict__ W1, const float* __restrict__ b1,
                                                 const float* __restrict__ W2, const float* __restrict__ b2,
                                                 const float* __restrict__ l1w, const float* __restrict__ l1b,
                                                 const float* __restrict__ l2w, const float* __restrict__ l2b,
                                                 float* __restrict__ xout) {
    __shared__ float A[64][68], B[64][68], W[64][68];
    __shared__ float w1s[64], b1s[64], w2s[64], b2s[64];
    int t = threadIdx.x;
    long row0 = (long)blockIdx.x * 64;
    stage_in(ctx, A, t, row0);
    stage_in(qin, B, t, row0);
    stage_wT(Wo, W, t);
    if (t < 64) { w1s[t] = l1w[t]; b1s[t] = l1b[t]; w2s[t] = l2w[t]; b2s[t] = l2b[t]; }
    __syncthreads();
    int tx = t & 15, ty = t >> 4, r0 = ty * 4, c0 = tx * 4;
    float x1[4][4] = {};
    gemm_tile(A, W, r0, c0, x1);
    {
        float4 b4 = *(const float4*)&bo[c0];
        float bv[4] = {b4.x, b4.y, b4.z, b4.w};
#pragma unroll
        for (int i = 0; i < 4; ++i)
#pragma unroll
            for (int j = 0; j < 4; ++j) x1[i][j] += bv[j] + B[r0 + i][c0 + j];
    }
    __syncthreads();
#pragma unroll
    for (int i = 0; i < 4; ++i) {
        float4 o; o.x = x1[i][0]; o.y = x1[i][1]; o.z = x1[i][2]; o.w = x1[i][3];
        *(float4*)&A[r0 + i][c0] = o;
    }
    __syncthreads();
    ln_rows2(A, B, w1s, b1s, w2s, b2s, t);
    stage_wT(W1, W, t);
    __syncthreads();
    float h[4][4] = {};
    gemm_tile(A, W, r0, c0, h);
    {
        float4 b4 = *(const float4*)&b1[c0];
        float bv[4] = {b4.x, b4.y, b4.z, b4.w};
#pragma unroll
        for (int i = 0; i < 4; ++i)
#pragma unroll
            for (int j = 0; j < 4; ++j) h[i][j] = fmaxf(h[i][j] + bv[j], 0.f);
    }
    __syncthreads();
#pragma unroll
    for (int i = 0; i < 4; ++i) {
        float4 o; o.x = h[i][0]; o.y = h[i][1]; o.z = h[i][2]; o.w = h[i][3];
        *(float4*)&A[r0 + i][c0] = o;
    }
    stage_wT(W2, W, t);
    __syncthreads();
    float o3[4][4] = {};
    gemm_tile(A, W, r0, c0, o3);
    {
        float4 b4 = *(const float4*)&b2[c0];
        float bv[4] = {b4.x, b4.y, b4.z, b4.w};
#pragma unroll
        for (int i = 0; i < 4; ++i) {
            float4 o;
            o.x = o3[i][0] + bv[0] + B[r0 + i][c0 + 0];
            o.y = o3[i][1] + bv[1] + B[r0 + i][c0 + 1];
            o.z = o3[i][2] + bv[2] + B[r0 + i][c0 + 2];
            o.w = o3[i][3] + bv[3] + B[r0 + i][c0 + 3];
            *(float4*)&xout[(row0 + r0 + i) * DDIM + c0] = o;
        }
    }
}

// ---------------- causal attention, one block per (b, head), 8 waves ----------------
// QK: K staged swizzled float4, per-row dot with 4 independent accumulators.
// PV: 4 rows per pass; V float4 (swizzled slot (d4+kk)&7); A_s per-row, zero-padded
// to the group's max row so the PV loop needs no causal gating.
__global__ __launch_bounds__(512) void attn_kernel(const float* __restrict__ q,
                                                   const float* __restrict__ k,
                                                   const float* __restrict__ v,
                                                   float* __restrict__ ctx) {
    __shared__ float K4[SS * 32];        // [(kk*8 + (dq^(kk&7)))*4 + e]
    __shared__ float V4[SS * 32];        // [(kk*8 + ((dq+kk)&7))*4 + e]
    __shared__ float A_s[8][4][SS];      // per-wave, per-row-in-group
    int b = blockIdx.x >> 1, h = blockIdx.x & 1;
    int t = threadIdx.x;
    const long base = (long)b * (SS * DDIM) + h * HD;
    for (int i = t; i < SS * 8; i += 512) {
        int kk = i >> 3, dq = i & 7;
        float4 k4 = *(const float4*)&k[base + kk * DDIM + dq * 4];
        *(float4*)&K4[(kk * 8 + (dq ^ (kk & 7))) * 4] = k4;
        float4 v4 = *(const float4*)&v[base + kk * DDIM + dq * 4];
        *(float4*)&V4[(kk * 8 + ((dq + kk) & 7)) * 4] = v4;
    }
    __syncthreads();
    int w = t >> 6, lane = t & 63;
    const float scale = 0.17677669529663687f;   // 1/sqrt(32)
    for (int G = w; G < SS / 4; G += 8) {
        int r3 = 4 * G + 3;
        int ncb3 = (r3 >> 6) + 1;
        // ---- QK + softmax, rows 4G..4G+3 ----
        for (int i = 0; i < 4; ++i) {
            int r = 4 * G + i;
            float4 qv4[8];
#pragma unroll
            for (int dq = 0; dq < 8; ++dq) qv4[dq] = *(const float4*)&q[base + r * DDIM + dq * 4];
            float sc[4];
            float m = -1e30f;
            for (int c = 0; c < ncb3; ++c) {
                int kk = lane + c * 64;
                sc[c] = -1e30f;
                if (kk <= r) {
                    int sw = kk & 7;
                    float d0 = 0.f, d1 = 0.f, d2 = 0.f, d3 = 0.f;
#pragma unroll
                    for (int dq = 0; dq < 8; ++dq) {
                        float4 k4 = *(const float4*)&K4[(kk * 8 + (dq ^ sw)) * 4];
                        d0 += qv4[dq].x * k4.x;
                        d1 += qv4[dq].y * k4.y;
                        d2 += qv4[dq].z * k4.z;
                        d3 += qv4[dq].w * k4.w;
                    }
                    sc[c] = ((d0 + d1) + (d2 + d3)) * scale;
                }
                m = fmaxf(m, sc[c]);
            }
            m = wave_max(m);
            float sum = 0.f;
            for (int c = 0; c < ncb3; ++c) {
                int kk = lane + c * 64;
                if (kk <= r) { sc[c] = __expf(sc[c] - m); sum += sc[c]; }
            }
            sum = wave_sum(sum);
            float inv = 1.f / sum;
            for (int c = 0; c < ncb3; ++c) {
                int kk = lane + c * 64;
                if (kk <= r3) A_s[w][i][kk] = (kk <= r) ? sc[c] * inv : 0.f;
            }
        }
        // ---- PV: 4 rows share each V read ----
        int d4 = lane & 7, ko = lane >> 3;
        float4 acc0 = {0,0,0,0}, acc1 = {0,0,0,0}, acc2 = {0,0,0,0}, acc3 = {0,0,0,0};
        for (int kk = ko; kk <= r3; kk += 8) {
            float4 v4 = *(const float4*)&V4[(kk * 8 + ((d4 + kk) & 7)) * 4];
            float a0 = A_s[w][0][kk], a1 = A_s[w][1][kk], a2 = A_s[w][2][kk], a3 = A_s[w][3][kk];
            acc0.x += a0 * v4.x; acc0.y += a0 * v4.y; acc0.z += a0 * v4.z; acc0.w += a0 * v4.w;
            acc1.x += a1 * v4.x; acc1.y += a1 * v4.y; acc1.z += a1 * v4.z; acc1.w += a1 * v4.w;
            acc2.x += a2 * v4.x; acc2.y += a2 * v4.y; acc2.z += a2 * v4.z; acc2.w += a2 * v4.w;
            acc3.x += a3 * v4.x; acc3.y += a3 * v4.y; acc3.z += a3 * v4.z; acc3.w += a3 * v4.w;
        }
        float4* accs[4] = {&acc0, &acc1, &acc2, &acc3};
#pragma unroll
        for (int i = 0; i < 4; ++i) {
            float4& a = *accs[i];
#pragma unroll
            for (int o = 8; o <= 32; o <<= 1) {
                a.x += __shfl_xor(a.x, o, 64);
                a.y += __shfl_xor(a.y, o, 64);
                a.z += __shfl_xor(a.z, o, 64);
                a.w += __shfl_xor(a.w, o, 64);
            }
        }
        if (ko == 0) {
#pragma unroll
            for (int i = 0; i < 4; ++i) {
                int r = 4 * G + i;
                *(float4*)&ctx[base + r * DDIM + d4 * 4] = *accs[i];
            }
        }
    }
}

// ---------------- Gram matrix partials ----------------
__global__ __launch_bounds__(256) void gram_kernel(const float* __restrict__ A, int nrows,
                                                   float* __restrict__ part) {
    __shared__ float rows[16][64];
    int t = threadIdx.x;
    int i = t >> 2;            // 0..63
    int jb = (t & 3) * 16;     // 0/16/32/48
    float acc[16] = {};
    for (long base = (long)blockIdx.x * 16; base < nrows; base += (long)GRAM_NB * 16) {
        {
            int rr = t >> 4, d4 = (t & 15) * 4;
            long gr = base + rr;
            float4 vv = make_float4(0.f, 0.f, 0.f, 0.f);
            if (gr < nrows) vv = *(const float4*)&A[gr * DDIM + d4];
            *(float4*)&rows[rr][d4] = vv;
        }
        __syncthreads();
#pragma unroll
        for (int rr = 0; rr < 16; ++rr) {
            float ai = rows[rr][i];
            float4 r0 = *(const float4*)&rows[rr][jb];
            float4 r1 = *(const float4*)&rows[rr][jb + 4];
            float4 r2 = *(const float4*)&rows[rr][jb + 8];
            float4 r3 = *(const float4*)&rows[rr][jb + 12];
            acc[0] += ai * r0.x; acc[1] += ai * r0.y; acc[2] += ai * r0.z; acc[3] += ai * r0.w;
            acc[4] += ai * r1.x; acc[5] += ai * r1.y; acc[6] += ai * r1.z; acc[7] += ai * r1.w;
            acc[8] += ai * r2.x; acc[9] += ai * r2.y; acc[10] += ai * r2.z; acc[11] += ai * r2.w;
            acc[12] += ai * r3.x; acc[13] += ai * r3.y; acc[14] += ai * r3.z; acc[15] += ai * r3.w;
        }
        __syncthreads();
    }
    float* slab = part + (long)blockIdx.x * 4096 + i * 64 + jb;
#pragma unroll
    for (int g = 0; g < 4; ++g) {
        float4 o; o.x = acc[g * 4]; o.y = acc[g * 4 + 1]; o.z = acc[g * 4 + 2]; o.w = acc[g * 4 + 3];
        *(float4*)&slab[g * 4] = o;
    }
}

// out[p] = sum_b part[b*4096+p]
__global__ __launch_bounds__(256) void gram_reduce(const float* __restrict__ part,
                                                   float* __restrict__ out) {
    int p = blockIdx.x * 256 + threadIdx.x;   // 16 blocks
    float s = 0.f;
    for (int b = 0; b < GRAM_NB; ++b) s += part[(long)b * 4096 + p];
    out[p] = s;
}

// ---------------- right(): per-block partial sums of (1-C)ps^2 - 2ps ----------------
__global__ __launch_bounds__(256) void right_kernel(const float* __restrict__ x,
                                                    const float* __restrict__ item_emb,
                                                    const int* __restrict__ pos_seqs,
                                                    const float* __restrict__ pred_w,
                                                    float* __restrict__ rpart) {
    __shared__ float p_s[64];
    __shared__ float red[4];
    int t = threadIdx.x;
    if (t < 64) p_s[t] = pred_w[t];
    __syncthreads();
    int w = t >> 6, lane = t & 63;
    float local = 0.f;
    for (long row = (long)blockIdx.x * 4 + w; row < NROWS; row += (long)gridDim.x * 4) {
        int pi = pos_seqs[row];
        float val = x[row * DDIM + lane] * item_emb[(long)pi * DDIM + lane] * p_s[lane];
        float ps = wave_sum(val);           // lane-uniform
        local += (1.0f - CC) * ps * ps - 2.0f * ps;   // identical on all 64 lanes
    }
    if (lane == 0) red[w] = local;
    __syncthreads();
    if (t == 0) rpart[blockIdx.x] = red[0] + red[1] + red[2] + red[3];
}

// ---------------- per-parameter sum-of-squares ----------------
struct NormEntry { const float* p; int n; };
struct NormArgs { NormEntry e[30]; };

__global__ __launch_bounds__(256) void norms_kernel(NormArgs args, float* __restrict__ norms) {
    __shared__ float red[256];
    NormEntry en = args.e[blockIdx.x];
    float s = 0.f;
    for (int i = threadIdx.x; i < en.n; i += 256) { float v = en.p[i]; s += v * v; }
    red[threadIdx.x] = s;
    for (int o = 128; o > 0; o >>= 1) {
        __syncthreads();
        if (threadIdx.x < o) red[threadIdx.x] += red[threadIdx.x + o];
    }
    __syncthreads();
    if (threadIdx.x == 0) norms[blockIdx.x] = red[0];
}

// ---------------- final scalar ----------------
__global__ __launch_bounds__(256) void final_kernel(const float* __restrict__ EE,
                                                    const float* __restrict__ FF,
                                                    const float* __restrict__ pred_w,
                                                    const float* __restrict__ rpart,
                                                    const float* __restrict__ norms,
                                                    float* __restrict__ out) {
    __shared__ float p_s[64];
    __shared__ float redL[256];
    __shared__ float redT[256];
    __shared__ float redR[256];
    int t = threadIdx.x;
    if (t < 64) p_s[t] = pred_w[t];
    __syncthreads();
    float lf = 0.f, tr = 0.f, rs = 0.f;
    for (int p = t; p < 4096; p += 256) {
        int i = p >> 6, j = p & 63;
        float ee = EE[p];
        lf += FF[p] * ee * p_s[i] * p_s[j];
        if (i == j) tr += ee;
    }
    for (int i = t; i < 1024; i += 256) rs += rpart[i];
    redL[t] = lf; redT[t] = tr; redR[t] = rs;
    for (int o = 128; o > 0; o >>= 1) {
        __syncthreads();
        if (t < o) { redL[t] += redL[t + o]; redT[t] += redT[t + o]; redR[t] += redR[t + o]; }
    }
    __syncthreads();
    if (t == 0) {
        float reg = sqrtf(redT[0]);   // ||item_emb||_F = sqrt(trace(EE))
        for (int s = 0; s < 30; ++s) reg += sqrtf(norms[s]);
        out[0] = CC * redL[0] + redR[0] + 0.1f * reg;
    }
}

// ---------------- host ----------------
struct DevPtrs { float *x, *qin, *q, *k, *v, *ctx, *gpart; };

static DevPtrs fetch_ptrs() {
    DevPtrs p;
    (void)hipGetSymbolAddress((void**)&p.x,    HIP_SYMBOL(g_x));
    (void)hipGetSymbolAddress((void**)&p.qin,  HIP_SYMBOL(g_qin));
    (void)hipGetSymbolAddress((void**)&p.q,    HIP_SYMBOL(g_q));
    (void)hipGetSymbolAddress((void**)&p.k,    HIP_SYMBOL(g_k));
    (void)hipGetSymbolAddress((void**)&p.v,    HIP_SYMBOL(g_v));
    (void)hipGetSymbolAddress((void**)&p.ctx,  HIP_SYMBOL(g_ctx));
    (void)hipGetSymbolAddress((void**)&p.gpart,HIP_SYMBOL(g_gpart));
    return p;
}

extern "C" void kernel_launch(void* const* d_in, const int* in_sizes, int n_in,
                              void* d_out, int out_size, void* d_ws, size_t ws_size,
                              hipStream_t stream) {
    const int*   log_seqs = (const int*)d_in[1];
    const int*   pos_seqs = (const int*)d_in[2];
    const float* item_emb = (const float*)d_in[3];
    const float* pos_emb  = (const float*)d_in[4];
    const float* pred_w   = (const float*)d_in[5];
    const float* ln_w     = (const float*)d_in[6];
    const float* ln_b     = (const float*)d_in[7];
    const float* qkv_w    = (const float*)d_in[8];
    const float* qkv_b    = (const float*)d_in[9];
    const float* out_w    = (const float*)d_in[10];
    const float* out_b    = (const float*)d_in[11];
    const float* fc1_w    = (const float*)d_in[12];
    const float* fc1_b    = (const float*)d_in[13];
    const float* ffln_w   = (const float*)d_in[14];
    const float* ffln_b   = (const float*)d_in[15];
    const float* fc2_w    = (const float*)d_in[16];
    const float* fc2_b    = (const float*)d_in[17];
    const float* ffln2_w  = (const float*)d_in[18];
    const float* ffln2_b  = (const float*)d_in[19];

    static DevPtrs P = fetch_ptrs();   // first call is the uncaptured correctness call

    float* ws    = (float*)d_ws;
    float* rpart = ws;            // 1024
    float* nrm   = ws + 1024;     // 30
    float* EE    = ws + 2048;     // 4096
    float* FF    = ws + 6144;     // 4096

    embed_kernel<<<NROWS * DDIM / 256, 256, 0, stream>>>(log_seqs, item_emb, pos_emb, P.x);

    const int GEMM_GRID = NROWS / 64;   // 1600

    for (int l = 0; l < LL; ++l) {
        const float* Wqkv = qkv_w + (long)l * 3 * 64 * 64;
        const float* Bqkv = qkv_b + (long)l * 192;
        qkv_fused<<<GEMM_GRID, 256, 0, stream>>>(
            P.x, Wqkv, Bqkv, ln_w + l * 64, ln_b + l * 64, P.qin, P.q, P.k, P.v);
        attn_kernel<<<BB * 2, 512, 0, stream>>>(P.q, P.k, P.v, P.ctx);
        ffn_fused<<<GEMM_GRID, 256, 0, stream>>>(
            P.ctx, P.qin,
            out_w + (long)l * 4096, out_b + l * 64,
            fc1_w + (long)l * 4096, fc1_b + l * 64,
            fc2_w + (long)l * 4096, fc2_b + l * 64,
            ffln_w + l * 64, ffln_b + l * 64,
            ffln2_w + l * 64, ffln2_b + l * 64,
            P.x);
    }

    gram_kernel<<<GRAM_NB, 256, 0, stream>>>(item_emb, 100001, P.gpart);
    gram_reduce<<<16, 256, 0, stream>>>(P.gpart, EE);
    gram_kernel<<<GRAM_NB, 256, 0, stream>>>(P.x, NROWS, P.gpart);
    gram_reduce<<<16, 256, 0, stream>>>(P.gpart, FF);
    right_kernel<<<1024, 256, 0, stream>>>(P.x, item_emb, pos_seqs, pred_w, rpart);

    NormArgs na;
    int s = 0;
    na.e[s++] = {pos_emb, (SS + 1) * DDIM};
    na.e[s++] = {pred_w, DDIM};
    for (int l = 0; l < LL; ++l) {
        na.e[s++] = {ln_w + l * 64, 64};
        na.e[s++] = {ln_b + l * 64, 64};
        na.e[s++] = {qkv_w + (long)l * 12288, 12288};
        na.e[s++] = {qkv_b + (long)l * 192, 192};
        na.e[s++] = {out_w + (long)l * 4096, 4096};
        na.e[s++] = {out_b + l * 64, 64};
        na.e[s++] = {fc1_w + (long)l * 4096, 4096};
        na.e[s++] = {fc1_b + l * 64, 64};
        na.e[s++] = {ffln_w + l * 64, 64};
        na.e[s++] = {ffln_b + l * 64, 64};
        na.e[s++] = {fc2_w + (long)l * 4096, 4096};
        na.e[s++] = {fc2_b + l * 64, 64};
        na.e[s++] = {ffln2_w + l * 64, 64};
        na.e[s++] = {ffln2_b + l * 64, 64};
    }
    norms_kernel<<<30, 256, 0, stream>>>(na, nrm);

    final_kernel<<<1, 256, 0, stream>>>(EE, FF, pred_w, rpart, nrm, (float*)d_out);
}

// Round 7
// 727.217 us; speedup vs baseline: 2.1270x; 1.0384x over previous
//
#include <hip/hip_runtime.h>
#include <math.h>

#define BB 512
#define SS 200
#define DDIM 64
#define HD 32
#define LL 2
#define NROWS (BB * SS)   // 102400
#define EPS 1e-8f
#define CC 0.001f
#define GRAM_NB 256

// ---------------- static device buffers (activations) ----------------
__device__ float g_x[NROWS * DDIM];
__device__ float g_qin[NROWS * DDIM];
__device__ float g_q[NROWS * DDIM];
__device__ float g_k[NROWS * DDIM];
__device__ float g_v[NROWS * DDIM];
__device__ float g_ctx[NROWS * DDIM];
__device__ float g_gpart[GRAM_NB * 4096];   // gram per-block partials

// ---------------- helpers ----------------
__device__ __forceinline__ float wave_sum(float v) {
#pragma unroll
    for (int o = 32; o > 0; o >>= 1) v += __shfl_xor(v, o, 64);
    return v;
}
__device__ __forceinline__ float wave_max(float v) {
#pragma unroll
    for (int o = 32; o > 0; o >>= 1) v = fmaxf(v, __shfl_xor(v, o, 64));
    return v;
}

// ---------------- embedding (float4) ----------------
__global__ __launch_bounds__(256) void embed_kernel(const int* __restrict__ log_seqs,
                                                    const float* __restrict__ item_emb,
                                                    const float* __restrict__ pos_emb,
                                                    float* __restrict__ x) {
    int tid = blockIdx.x * 256 + threadIdx.x;   // over NROWS*16
    int row = tid >> 4, q4 = tid & 15;
    int s = row % SS;
    int li = log_seqs[row];
    int poss = li ? (s + 1) : 0;
    float4 e = *(const float4*)&item_emb[li * DDIM + q4 * 4];
    float4 p = *(const float4*)&pos_emb[poss * DDIM + q4 * 4];
    float4 o;
    o.x = e.x * 8.0f + p.x; o.y = e.y * 8.0f + p.y;
    o.z = e.z * 8.0f + p.z; o.w = e.w * 8.0f + p.w;
    *(float4*)&x[row * DDIM + q4 * 4] = o;
}

// ---------------- tile staging helpers ----------------
__device__ __forceinline__ void stage_in(const float* __restrict__ G, float (* __restrict__ tile)[68],
                                         int t, long row0) {
#pragma unroll
    for (int rep = 0; rep < 4; ++rep) {
        int idx = t + rep * 256;
        int c = idx >> 4, d4 = (idx & 15) * 4;
        *(float4*)&tile[c][d4] = *(const float4*)&G[(row0 + c) * DDIM + d4];
    }
}

// Stage W (64 out x 64 in, row-major) TRANSPOSED into wt[d][c], via 4x4 block transpose.
__device__ __forceinline__ void stage_wT(const float* __restrict__ Wg, float (* __restrict__ wt)[68], int t) {
    int bi = t & 15, bj = t >> 4;   // bi: c-block, bj: d-block
    float rv[4][4];
#pragma unroll
    for (int e = 0; e < 4; ++e)
        *(float4*)rv[e] = *(const float4*)&Wg[(bi * 4 + e) * DDIM + bj * 4];
#pragma unroll
    for (int e = 0; e < 4; ++e) {
        float4 o;
        o.x = rv[0][e]; o.y = rv[1][e]; o.z = rv[2][e]; o.w = rv[3][e];
        *(float4*)&wt[bj * 4 + e][bi * 4] = o;
    }
}

// acc[i][j] += sum_d A[r0+i][d] * W[d][c0+j]   (W stored transposed: wt[d][c])
__device__ __forceinline__ void gemm_tile(const float (* __restrict__ A)[68],
                                          const float (* __restrict__ W)[68],
                                          int r0, int c0, float acc[4][4]) {
#pragma unroll
    for (int d = 0; d < 64; d += 4) {
        float4 a[4], wv[4];
#pragma unroll
        for (int i = 0; i < 4; ++i) a[i] = *(const float4*)&A[r0 + i][d];
#pragma unroll
        for (int tt = 0; tt < 4; ++tt) wv[tt] = *(const float4*)&W[d + tt][c0];
#pragma unroll
        for (int i = 0; i < 4; ++i) {
            float av[4] = {a[i].x, a[i].y, a[i].z, a[i].w};
#pragma unroll
            for (int tt = 0; tt < 4; ++tt) {
                acc[i][0] += av[tt] * wv[tt].x;
                acc[i][1] += av[tt] * wv[tt].y;
                acc[i][2] += av[tt] * wv[tt].z;
                acc[i][3] += av[tt] * wv[tt].w;
            }
        }
    }
}

// LayerNorm rows of src -> dst (thread t owns row t>>2, 16-col chunk (t&3)*16).
__device__ __forceinline__ void ln_rows(const float (* __restrict__ src)[68], float (* __restrict__ dst)[68],
                                        const float* __restrict__ w_s, const float* __restrict__ b_s,
                                        int t, float* __restrict__ save) {
    int rr = t >> 2, qd = (t & 3) * 16;
    float4 v[4];
#pragma unroll
    for (int g = 0; g < 4; ++g) v[g] = *(const float4*)&src[rr][qd + g * 4];
    float s1 = 0.f, s2 = 0.f;
#pragma unroll
    for (int g = 0; g < 4; ++g) {
        s1 += (v[g].x + v[g].y) + (v[g].z + v[g].w);
        s2 += (v[g].x * v[g].x + v[g].y * v[g].y) + (v[g].z * v[g].z + v[g].w * v[g].w);
    }
    s1 += __shfl_xor(s1, 1, 64); s1 += __shfl_xor(s1, 2, 64);
    s2 += __shfl_xor(s2, 1, 64); s2 += __shfl_xor(s2, 2, 64);
    float m = s1 * (1.f / 64.f);
    float var = s2 * (1.f / 64.f) - m * m;
    float rs = rsqrtf(var + EPS);
#pragma unroll
    for (int g = 0; g < 4; ++g) {
        float4 w4 = *(const float4*)&w_s[qd + g * 4];
        float4 b4 = *(const float4*)&b_s[qd + g * 4];
        float4 o;
        o.x = (v[g].x - m) * rs * w4.x + b4.x;
        o.y = (v[g].y - m) * rs * w4.y + b4.y;
        o.z = (v[g].z - m) * rs * w4.z + b4.z;
        o.w = (v[g].w - m) * rs * w4.w + b4.w;
        *(float4*)&dst[rr][qd + g * 4] = o;
        if (save) *(float4*)&save[rr * DDIM + qd + g * 4] = o;
    }
}

// Dual LayerNorm: a := LN1(a), b := LN2(a_old)
__device__ __forceinline__ void ln_rows2(float (* __restrict__ a)[68], float (* __restrict__ b)[68],
                                         const float* __restrict__ w1, const float* __restrict__ b1,
                                         const float* __restrict__ w2, const float* __restrict__ b2, int t) {
    int rr = t >> 2, qd = (t & 3) * 16;
    float4 v[4];
#pragma unroll
    for (int g = 0; g < 4; ++g) v[g] = *(const float4*)&a[rr][qd + g * 4];
    float s1 = 0.f, s2 = 0.f;
#pragma unroll
    for (int g = 0; g < 4; ++g) {
        s1 += (v[g].x + v[g].y) + (v[g].z + v[g].w);
        s2 += (v[g].x * v[g].x + v[g].y * v[g].y) + (v[g].z * v[g].z + v[g].w * v[g].w);
    }
    s1 += __shfl_xor(s1, 1, 64); s1 += __shfl_xor(s1, 2, 64);
    s2 += __shfl_xor(s2, 1, 64); s2 += __shfl_xor(s2, 2, 64);
    float m = s1 * (1.f / 64.f);
    float var = s2 * (1.f / 64.f) - m * m;
    float rs = rsqrtf(var + EPS);
#pragma unroll
    for (int g = 0; g < 4; ++g) {
        float4 w14 = *(const float4*)&w1[qd + g * 4];
        float4 b14 = *(const float4*)&b1[qd + g * 4];
        float4 w24 = *(const float4*)&w2[qd + g * 4];
        float4 b24 = *(const float4*)&b2[qd + g * 4];
        float nx = (v[g].x - m) * rs, ny = (v[g].y - m) * rs, nz = (v[g].z - m) * rs, nw = (v[g].w - m) * rs;
        float4 o1, o2;
        o1.x = nx * w14.x + b14.x; o1.y = ny * w14.y + b14.y; o1.z = nz * w14.z + b14.z; o1.w = nw * w14.w + b14.w;
        o2.x = nx * w24.x + b24.x; o2.y = ny * w24.y + b24.y; o2.z = nz * w24.z + b24.z; o2.w = nw * w24.w + b24.w;
        *(float4*)&a[rr][qd + g * 4] = o1;
        *(float4*)&b[rr][qd + g * 4] = o2;
    }
}

// ---------------- fused QKV ----------------
__global__ __launch_bounds__(256) void qkv_fused(const float* __restrict__ x,
                                                 const float* __restrict__ Wqkv,
                                                 const float* __restrict__ Bqkv,
                                                 const float* __restrict__ lnw,
                                                 const float* __restrict__ lnb,
                                                 float* __restrict__ qin,
                                                 float* __restrict__ qo,
                                                 float* __restrict__ ko,
                                                 float* __restrict__ vo) {
    __shared__ float A[64][68], B[64][68], W[64][68];
    __shared__ float lw[64], lb[64];
    int t = threadIdx.x;
    long row0 = (long)blockIdx.x * 64;
    stage_in(x, A, t, row0);
    stage_wT(Wqkv, W, t);
    if (t < 64) { lw[t] = lnw[t]; lb[t] = lnb[t]; }
    __syncthreads();
    ln_rows(A, B, lw, lb, t, qin + row0 * DDIM);
    __syncthreads();
    int tx = t & 15, ty = t >> 4, r0 = ty * 4, c0 = tx * 4;
    {
        float acc[4][4] = {};
        gemm_tile(B, W, r0, c0, acc);
        float4 b4 = *(const float4*)&Bqkv[c0];
        float bv[4] = {b4.x, b4.y, b4.z, b4.w};
#pragma unroll
        for (int i = 0; i < 4; ++i) {
            float4 o; o.x = acc[i][0] + bv[0]; o.y = acc[i][1] + bv[1]; o.z = acc[i][2] + bv[2]; o.w = acc[i][3] + bv[3];
            *(float4*)&qo[(row0 + r0 + i) * DDIM + c0] = o;
        }
    }
    __syncthreads();
    stage_wT(Wqkv + 4096, W, t);
    __syncthreads();
    {
        float acc[4][4] = {};
        gemm_tile(A, W, r0, c0, acc);
        float4 b4 = *(const float4*)&Bqkv[64 + c0];
        float bv[4] = {b4.x, b4.y, b4.z, b4.w};
#pragma unroll
        for (int i = 0; i < 4; ++i) {
            float4 o; o.x = acc[i][0] + bv[0]; o.y = acc[i][1] + bv[1]; o.z = acc[i][2] + bv[2]; o.w = acc[i][3] + bv[3];
            *(float4*)&ko[(row0 + r0 + i) * DDIM + c0] = o;
        }
    }
    __syncthreads();
    stage_wT(Wqkv + 8192, W, t);
    __syncthreads();
    {
        float acc[4][4] = {};
        gemm_tile(A, W, r0, c0, acc);
        float4 b4 = *(const float4*)&Bqkv[128 + c0];
        float bv[4] = {b4.x, b4.y, b4.z, b4.w};
#pragma unroll
        for (int i = 0; i < 4; ++i) {
            float4 o; o.x = acc[i][0] + bv[0]; o.y = acc[i][1] + bv[1]; o.z = acc[i][2] + bv[2]; o.w = acc[i][3] + bv[3];
            *(float4*)&vo[(row0 + r0 + i) * DDIM + c0] = o;
        }
    }
}

// ---------------- fused out-proj + FFN ----------------
__global__ __launch_bounds__(256) void ffn_fused(const float* __restrict__ ctx,
                                                 const float* __restrict__ qin,
                                                 const float* __restrict__ Wo, const float* __restrict__ bo,
                                                 const float* __restrict__ W1, const float* __restrict__ b1,
                                                 const float* __restrict__ W2, const float* __restrict__ b2,
                                                 const float* __restrict__ l1w, const float* __restrict__ l1b,
                                                 const float* __restrict__ l2w, const float* __restrict__ l2b,
                                                 float* __restrict__ xout) {
    __shared__ float A[64][68], B[64][68], W[64][68];
    __shared__ float w1s[64], b1s[64], w2s[64], b2s[64];
    int t = threadIdx.x;
    long row0 = (long)blockIdx.x * 64;
    stage_in(ctx, A, t, row0);
    stage_in(qin, B, t, row0);
    stage_wT(Wo, W, t);
    if (t < 64) { w1s[t] = l1w[t]; b1s[t] = l1b[t]; w2s[t] = l2w[t]; b2s[t] = l2b[t]; }
    __syncthreads();
    int tx = t & 15, ty = t >> 4, r0 = ty * 4, c0 = tx * 4;
    float x1[4][4] = {};
    gemm_tile(A, W, r0, c0, x1);
    {
        float4 b4 = *(const float4*)&bo[c0];
        float bv[4] = {b4.x, b4.y, b4.z, b4.w};
#pragma unroll
        for (int i = 0; i < 4; ++i)
#pragma unroll
            for (int j = 0; j < 4; ++j) x1[i][j] += bv[j] + B[r0 + i][c0 + j];
    }
    __syncthreads();
#pragma unroll
    for (int i = 0; i < 4; ++i) {
        float4 o; o.x = x1[i][0]; o.y = x1[i][1]; o.z = x1[i][2]; o.w = x1[i][3];
        *(float4*)&A[r0 + i][c0] = o;
    }
    __syncthreads();
    ln_rows2(A, B, w1s, b1s, w2s, b2s, t);
    stage_wT(W1, W, t);
    __syncthreads();
    float h[4][4] = {};
    gemm_tile(A, W, r0, c0, h);
    {
        float4 b4 = *(const float4*)&b1[c0];
        float bv[4] = {b4.x, b4.y, b4.z, b4.w};
#pragma unroll
        for (int i = 0; i < 4; ++i)
#pragma unroll
            for (int j = 0; j < 4; ++j) h[i][j] = fmaxf(h[i][j] + bv[j], 0.f);
    }
    __syncthreads();
#pragma unroll
    for (int i = 0; i < 4; ++i) {
        float4 o; o.x = h[i][0]; o.y = h[i][1]; o.z = h[i][2]; o.w = h[i][3];
        *(float4*)&A[r0 + i][c0] = o;
    }
    stage_wT(W2, W, t);
    __syncthreads();
    float o3[4][4] = {};
    gemm_tile(A, W, r0, c0, o3);
    {
        float4 b4 = *(const float4*)&b2[c0];
        float bv[4] = {b4.x, b4.y, b4.z, b4.w};
#pragma unroll
        for (int i = 0; i < 4; ++i) {
            float4 o;
            o.x = o3[i][0] + bv[0] + B[r0 + i][c0 + 0];
            o.y = o3[i][1] + bv[1] + B[r0 + i][c0 + 1];
            o.z = o3[i][2] + bv[2] + B[r0 + i][c0 + 2];
            o.w = o3[i][3] + bv[3] + B[r0 + i][c0 + 3];
            *(float4*)&xout[(row0 + r0 + i) * DDIM + c0] = o;
        }
    }
}

// ---------------- causal attention, one block per (b, head), 8 waves ----------------
// QK chunk-major: per key-chunk each lane loads its K row into registers ONCE and
// dots against all 4 Q-rows of the group (Q via wave-uniform global broadcast loads).
// PV: 4 rows share each V float4 read; A_s zero-padded to group max row.
__global__ __launch_bounds__(512) void attn_kernel(const float* __restrict__ q,
                                                   const float* __restrict__ k,
                                                   const float* __restrict__ v,
                                                   float* __restrict__ ctx) {
    __shared__ float K4[SS * 32];        // [(kk*8 + (dq^(kk&7)))*4 + e]
    __shared__ float V4[SS * 32];        // [(kk*8 + ((dq+kk)&7))*4 + e]
    __shared__ float A_s[8][4][SS];      // per-wave, per-row-in-group
    int b = blockIdx.x >> 1, h = blockIdx.x & 1;
    int t = threadIdx.x;
    const long base = (long)b * (SS * DDIM) + h * HD;
    for (int i = t; i < SS * 8; i += 512) {
        int kk = i >> 3, dq = i & 7;
        float4 k4 = *(const float4*)&k[base + kk * DDIM + dq * 4];
        *(float4*)&K4[(kk * 8 + (dq ^ (kk & 7))) * 4] = k4;
        float4 v4 = *(const float4*)&v[base + kk * DDIM + dq * 4];
        *(float4*)&V4[(kk * 8 + ((dq + kk) & 7)) * 4] = v4;
    }
    __syncthreads();
    int w = t >> 6, lane = t & 63;
    const float scale = 0.17677669529663687f;   // 1/sqrt(32)
    for (int G = w; G < SS / 4; G += 8) {
        int r3 = 4 * G + 3;
        int ncb3 = (r3 >> 6) + 1;            // 1..4
        float sc[4][4];
#pragma unroll
        for (int i = 0; i < 4; ++i)
#pragma unroll
            for (int c = 0; c < 4; ++c) sc[i][c] = -1e30f;
        // ---- QK, chunk-major: K row regs reused across 4 Q-rows ----
#pragma unroll
        for (int c = 0; c < 4; ++c) {
            if (c < ncb3) {
                int kk = lane + c * 64;
                if (kk <= r3) {
                    int sw = kk & 7;
                    float4 kv[8];
#pragma unroll
                    for (int dq = 0; dq < 8; ++dq)
                        kv[dq] = *(const float4*)&K4[(kk * 8 + (dq ^ sw)) * 4];
#pragma unroll
                    for (int i = 0; i < 4; ++i) {
                        int r = 4 * G + i;
                        if (kk <= r) {
                            const float4* qp = (const float4*)&q[base + r * DDIM];
                            float d0 = 0.f, d1 = 0.f, d2 = 0.f, d3 = 0.f;
#pragma unroll
                            for (int dq = 0; dq < 8; ++dq) {
                                float4 q4 = qp[dq];
                                d0 += q4.x * kv[dq].x;
                                d1 += q4.y * kv[dq].y;
                                d2 += q4.z * kv[dq].z;
                                d3 += q4.w * kv[dq].w;
                            }
                            sc[i][c] = ((d0 + d1) + (d2 + d3)) * scale;
                        }
                    }
                }
            }
        }
        // ---- softmax per row ----
#pragma unroll
        for (int i = 0; i < 4; ++i) {
            int r = 4 * G + i;
            float m = -1e30f;
#pragma unroll
            for (int c = 0; c < 4; ++c) if (c < ncb3) m = fmaxf(m, sc[i][c]);
            m = wave_max(m);
            float sum = 0.f;
#pragma unroll
            for (int c = 0; c < 4; ++c) {
                if (c < ncb3) {
                    int kk = lane + c * 64;
                    if (kk <= r) { sc[i][c] = __expf(sc[i][c] - m); sum += sc[i][c]; }
                }
            }
            sum = wave_sum(sum);
            float inv = 1.f / sum;
#pragma unroll
            for (int c = 0; c < 4; ++c) {
                if (c < ncb3) {
                    int kk = lane + c * 64;
                    if (kk <= r3) A_s[w][i][kk] = (kk <= r) ? sc[i][c] * inv : 0.f;
                }
            }
        }
        // ---- PV: 4 rows share each V read ----
        int d4 = lane & 7, ko = lane >> 3;
        float4 acc0 = {0,0,0,0}, acc1 = {0,0,0,0}, acc2 = {0,0,0,0}, acc3 = {0,0,0,0};
        for (int kk = ko; kk <= r3; kk += 8) {
            float4 v4 = *(const float4*)&V4[(kk * 8 + ((d4 + kk) & 7)) * 4];
            float a0 = A_s[w][0][kk], a1 = A_s[w][1][kk], a2 = A_s[w][2][kk], a3 = A_s[w][3][kk];
            acc0.x += a0 * v4.x; acc0.y += a0 * v4.y; acc0.z += a0 * v4.z; acc0.w += a0 * v4.w;
            acc1.x += a1 * v4.x; acc1.y += a1 * v4.y; acc1.z += a1 * v4.z; acc1.w += a1 * v4.w;
            acc2.x += a2 * v4.x; acc2.y += a2 * v4.y; acc2.z += a2 * v4.z; acc2.w += a2 * v4.w;
            acc3.x += a3 * v4.x; acc3.y += a3 * v4.y; acc3.z += a3 * v4.z; acc3.w += a3 * v4.w;
        }
        float4* accs[4] = {&acc0, &acc1, &acc2, &acc3};
#pragma unroll
        for (int i = 0; i < 4; ++i) {
            float4& a = *accs[i];
#pragma unroll
            for (int o = 8; o <= 32; o <<= 1) {
                a.x += __shfl_xor(a.x, o, 64);
                a.y += __shfl_xor(a.y, o, 64);
                a.z += __shfl_xor(a.z, o, 64);
                a.w += __shfl_xor(a.w, o, 64);
            }
        }
        if (ko == 0) {
#pragma unroll
            for (int i = 0; i < 4; ++i) {
                int r = 4 * G + i;
                *(float4*)&ctx[base + r * DDIM + d4 * 4] = *accs[i];
            }
        }
    }
}

// ---------------- Gram matrix partials ----------------
__global__ __launch_bounds__(256) void gram_kernel(const float* __restrict__ A, int nrows,
                                                   float* __restrict__ part) {
    __shared__ float rows[16][64];
    int t = threadIdx.x;
    int i = t >> 2;            // 0..63
    int jb = (t & 3) * 16;     // 0/16/32/48
    float acc[16] = {};
    for (long base = (long)blockIdx.x * 16; base < nrows; base += (long)GRAM_NB * 16) {
        {
            int rr = t >> 4, d4 = (t & 15) * 4;
            long gr = base + rr;
            float4 vv = make_float4(0.f, 0.f, 0.f, 0.f);
            if (gr < nrows) vv = *(const float4*)&A[gr * DDIM + d4];
            *(float4*)&rows[rr][d4] = vv;
        }
        __syncthreads();
#pragma unroll
        for (int rr = 0; rr < 16; ++rr) {
            float ai = rows[rr][i];
            float4 r0 = *(const float4*)&rows[rr][jb];
            float4 r1 = *(const float4*)&rows[rr][jb + 4];
            float4 r2 = *(const float4*)&rows[rr][jb + 8];
            float4 r3 = *(const float4*)&rows[rr][jb + 12];
            acc[0] += ai * r0.x; acc[1] += ai * r0.y; acc[2] += ai * r0.z; acc[3] += ai * r0.w;
            acc[4] += ai * r1.x; acc[5] += ai * r1.y; acc[6] += ai * r1.z; acc[7] += ai * r1.w;
            acc[8] += ai * r2.x; acc[9] += ai * r2.y; acc[10] += ai * r2.z; acc[11] += ai * r2.w;
            acc[12] += ai * r3.x; acc[13] += ai * r3.y; acc[14] += ai * r3.z; acc[15] += ai * r3.w;
        }
        __syncthreads();
    }
    float* slab = part + (long)blockIdx.x * 4096 + i * 64 + jb;
#pragma unroll
    for (int g = 0; g < 4; ++g) {
        float4 o; o.x = acc[g * 4]; o.y = acc[g * 4 + 1]; o.z = acc[g * 4 + 2]; o.w = acc[g * 4 + 3];
        *(float4*)&slab[g * 4] = o;
    }
}

// out[p] = sum_b part[b*4096+p]
__global__ __launch_bounds__(256) void gram_reduce(const float* __restrict__ part,
                                                   float* __restrict__ out) {
    int p = blockIdx.x * 256 + threadIdx.x;   // 16 blocks
    float s = 0.f;
    for (int b = 0; b < GRAM_NB; ++b) s += part[(long)b * 4096 + p];
    out[p] = s;
}

// ---------------- right(): per-block partial sums of (1-C)ps^2 - 2ps ----------------
__global__ __launch_bounds__(256) void right_kernel(const float* __restrict__ x,
                                                    const float* __restrict__ item_emb,
                                                    const int* __restrict__ pos_seqs,
                                                    const float* __restrict__ pred_w,
                                                    float* __restrict__ rpart) {
    __shared__ float p_s[64];
    __shared__ float red[4];
    int t = threadIdx.x;
    if (t < 64) p_s[t] = pred_w[t];
    __syncthreads();
    int w = t >> 6, lane = t & 63;
    float local = 0.f;
    for (long row = (long)blockIdx.x * 4 + w; row < NROWS; row += (long)gridDim.x * 4) {
        int pi = pos_seqs[row];
        float val = x[row * DDIM + lane] * item_emb[(long)pi * DDIM + lane] * p_s[lane];
        float ps = wave_sum(val);           // lane-uniform
        local += (1.0f - CC) * ps * ps - 2.0f * ps;   // identical on all 64 lanes
    }
    if (lane == 0) red[w] = local;
    __syncthreads();
    if (t == 0) rpart[blockIdx.x] = red[0] + red[1] + red[2] + red[3];
}

// ---------------- per-parameter sum-of-squares ----------------
struct NormEntry { const float* p; int n; };
struct NormArgs { NormEntry e[30]; };

__global__ __launch_bounds__(256) void norms_kernel(NormArgs args, float* __restrict__ norms) {
    __shared__ float red[256];
    NormEntry en = args.e[blockIdx.x];
    float s = 0.f;
    for (int i = threadIdx.x; i < en.n; i += 256) { float v = en.p[i]; s += v * v; }
    red[threadIdx.x] = s;
    for (int o = 128; o > 0; o >>= 1) {
        __syncthreads();
        if (threadIdx.x < o) red[threadIdx.x] += red[threadIdx.x + o];
    }
    __syncthreads();
    if (threadIdx.x == 0) norms[blockIdx.x] = red[0];
}

// ---------------- final scalar ----------------
__global__ __launch_bounds__(256) void final_kernel(const float* __restrict__ EE,
                                                    const float* __restrict__ FF,
                                                    const float* __restrict__ pred_w,
                                                    const float* __restrict__ rpart,
                                                    const float* __restrict__ norms,
                                                    float* __restrict__ out) {
    __shared__ float p_s[64];
    __shared__ float redL[256];
    __shared__ float redT[256];
    __shared__ float redR[256];
    int t = threadIdx.x;
    if (t < 64) p_s[t] = pred_w[t];
    __syncthreads();
    float lf = 0.f, tr = 0.f, rs = 0.f;
    for (int p = t; p < 4096; p += 256) {
        int i = p >> 6, j = p & 63;
        float ee = EE[p];
        lf += FF[p] * ee * p_s[i] * p_s[j];
        if (i == j) tr += ee;
    }
    for (int i = t; i < 1024; i += 256) rs += rpart[i];
    redL[t] = lf; redT[t] = tr; redR[t] = rs;
    for (int o = 128; o > 0; o >>= 1) {
        __syncthreads();
        if (t < o) { redL[t] += redL[t + o]; redT[t] += redT[t + o]; redR[t] += redR[t + o]; }
    }
    __syncthreads();
    if (t == 0) {
        float reg = sqrtf(redT[0]);   // ||item_emb||_F = sqrt(trace(EE))
        for (int s = 0; s < 30; ++s) reg += sqrtf(norms[s]);
        out[0] = CC * redL[0] + redR[0] + 0.1f * reg;
    }
}

// ---------------- host ----------------
struct DevPtrs { float *x, *qin, *q, *k, *v, *ctx, *gpart; };

static DevPtrs fetch_ptrs() {
    DevPtrs p;
    (void)hipGetSymbolAddress((void**)&p.x,    HIP_SYMBOL(g_x));
    (void)hipGetSymbolAddress((void**)&p.qin,  HIP_SYMBOL(g_qin));
    (void)hipGetSymbolAddress((void**)&p.q,    HIP_SYMBOL(g_q));
    (void)hipGetSymbolAddress((void**)&p.k,    HIP_SYMBOL(g_k));
    (void)hipGetSymbolAddress((void**)&p.v,    HIP_SYMBOL(g_v));
    (void)hipGetSymbolAddress((void**)&p.ctx,  HIP_SYMBOL(g_ctx));
    (void)hipGetSymbolAddress((void**)&p.gpart,HIP_SYMBOL(g_gpart));
    return p;
}

extern "C" void kernel_launch(void* const* d_in, const int* in_sizes, int n_in,
                              void* d_out, int out_size, void* d_ws, size_t ws_size,
                              hipStream_t stream) {
    const int*   log_seqs = (const int*)d_in[1];
    const int*   pos_seqs = (const int*)d_in[2];
    const float* item_emb = (const float*)d_in[3];
    const float* pos_emb  = (const float*)d_in[4];
    const float* pred_w   = (const float*)d_in[5];
    const float* ln_w     = (const float*)d_in[6];
    const float* ln_b     = (const float*)d_in[7];
    const float* qkv_w    = (const float*)d_in[8];
    const float* qkv_b    = (const float*)d_in[9];
    const float* out_w    = (const float*)d_in[10];
    const float* out_b    = (const float*)d_in[11];
    const float* fc1_w    = (const float*)d_in[12];
    const float* fc1_b    = (const float*)d_in[13];
    const float* ffln_w   = (const float*)d_in[14];
    const float* ffln_b   = (const float*)d_in[15];
    const float* fc2_w    = (const float*)d_in[16];
    const float* fc2_b    = (const float*)d_in[17];
    const float* ffln2_w  = (const float*)d_in[18];
    const float* ffln2_b  = (const float*)d_in[19];

    static DevPtrs P = fetch_ptrs();   // first call is the uncaptured correctness call

    float* ws    = (float*)d_ws;
    float* rpart = ws;            // 1024
    float* nrm   = ws + 1024;     // 30
    float* EE    = ws + 2048;     // 4096
    float* FF    = ws + 6144;     // 4096

    embed_kernel<<<NROWS * 16 / 256, 256, 0, stream>>>(log_seqs, item_emb, pos_emb, P.x);

    const int GEMM_GRID = NROWS / 64;   // 1600

    for (int l = 0; l < LL; ++l) {
        const float* Wqkv = qkv_w + (long)l * 3 * 64 * 64;
        const float* Bqkv = qkv_b + (long)l * 192;
        qkv_fused<<<GEMM_GRID, 256, 0, stream>>>(
            P.x, Wqkv, Bqkv, ln_w + l * 64, ln_b + l * 64, P.qin, P.q, P.k, P.v);
        attn_kernel<<<BB * 2, 512, 0, stream>>>(P.q, P.k, P.v, P.ctx);
        ffn_fused<<<GEMM_GRID, 256, 0, stream>>>(
            P.ctx, P.qin,
            out_w + (long)l * 4096, out_b + l * 64,
            fc1_w + (long)l * 4096, fc1_b + l * 64,
            fc2_w + (long)l * 4096, fc2_b + l * 64,
            ffln_w + l * 64, ffln_b + l * 64,
            ffln2_w + l * 64, ffln2_b + l * 64,
            P.x);
    }

    gram_kernel<<<GRAM_NB, 256, 0, stream>>>(item_emb, 100001, P.gpart);
    gram_reduce<<<16, 256, 0, stream>>>(P.gpart, EE);
    gram_kernel<<<GRAM_NB, 256, 0, stream>>>(P.x, NROWS, P.gpart);
    gram_reduce<<<16, 256, 0, stream>>>(P.gpart, FF);
    right_kernel<<<1024, 256, 0, stream>>>(P.x, item_emb, pos_seqs, pred_w, rpart);

    NormArgs na;
    int s = 0;
    na.e[s++] = {pos_emb, (SS + 1) * DDIM};
    na.e[s++] = {pred_w, DDIM};
    for (int l = 0; l < LL; ++l) {
        na.e[s++] = {ln_w + l * 64, 64};
        na.e[s++] = {ln_b + l * 64, 64};
        na.e[s++] = {qkv_w + (long)l * 12288, 12288};
        na.e[s++] = {qkv_b + (long)l * 192, 192};
        na.e[s++] = {out_w + (long)l * 4096, 4096};
        na.e[s++] = {out_b + l * 64, 64};
        na.e[s++] = {fc1_w + (long)l * 4096, 4096};
        na.e[s++] = {fc1_b + l * 64, 64};
        na.e[s++] = {ffln_w + l * 64, 64};
        na.e[s++] = {ffln_b + l * 64, 64};
        na.e[s++] = {fc2_w + (long)l * 4096, 4096};
        na.e[s++] = {fc2_b + l * 64, 64};
        na.e[s++] = {ffln2_w + l * 64, 64};
        na.e[s++] = {ffln2_b + l * 64, 64};
    }
    norms_kernel<<<30, 256, 0, stream>>>(na, nrm);

    final_kernel<<<1, 256, 0, stream>>>(EE, FF, pred_w, rpart, nrm, (float*)d_out);
}